// Round 10
// baseline (318.185 us; speedup 1.0000x reference)
//
#include <hip/hip_runtime.h>
#include <hip/hip_bf16.h>

// ViT encoder block: B=8, N=1024, C=768, H=12, DH=64, FF=3072, fp32 in/out,
// bf16 MFMA compute internally.
#define BDIM 8
#define SEQ  1024
#define CH   768
#define NHD  12
#define DHD  64
#define FFD  3072
#define MR   (BDIM*SEQ)   // 8192 token rows

typedef __attribute__((ext_vector_type(8))) short bf16x8;
typedef __attribute__((ext_vector_type(4))) float f32x4;
typedef unsigned int   u32;
typedef unsigned short u16;

__device__ __forceinline__ u16 f2bfu(float x) {
  __hip_bfloat16 h = __float2bfloat16(x);
  return *reinterpret_cast<u16*>(&h);
}

__device__ __forceinline__ void glds16(const void* g, void* l) {
  __builtin_amdgcn_global_load_lds(
      (const __attribute__((address_space(1))) u32*)g,
      (__attribute__((address_space(3))) u32*)l, 16, 0, 0);
}

// ---------------------------------------------------------------- transpose
// All 6 weights in one launch. W [K][Nc] fp32 -> Wt [Nc][K] bf16 in ws.
__global__ __launch_bounds__(256) void k_transpose_all(
    const float* __restrict__ Wq, const float* __restrict__ Wk,
    const float* __restrict__ Wv, const float* __restrict__ Wo,
    const float* __restrict__ W1, const float* __restrict__ W2,
    u16* __restrict__ ws) {
  __shared__ float tile[32][33];
  int b = blockIdx.x;
  int id, tb;
  if (b < 2304)      { id = b / 576; tb = b % 576; }
  else if (b < 4608) { id = 4;       tb = b - 2304; }
  else               { id = 5;       tb = b - 4608; }
  const float* src;
  u16* dst;
  int K, Nc;
  switch (id) {
    case 0: src = Wq; dst = ws;                      K = CH;  Nc = CH;  break;
    case 1: src = Wk; dst = ws + (size_t)CH*CH;      K = CH;  Nc = CH;  break;
    case 2: src = Wv; dst = ws + (size_t)2*CH*CH;    K = CH;  Nc = CH;  break;
    case 3: src = Wo; dst = ws + (size_t)3*CH*CH;    K = CH;  Nc = CH;  break;
    case 4: src = W1; dst = ws + (size_t)4*CH*CH;    K = CH;  Nc = FFD; break;
    default:src = W2; dst = ws + (size_t)4*CH*CH + (size_t)CH*FFD;
                                                     K = FFD; Nc = CH;  break;
  }
  int tilesx = Nc >> 5;
  int bx = (tb % tilesx) * 32;        // Nc dim
  int by = (tb / tilesx) * 32;        // K dim
  int tx = threadIdx.x & 31, ty = threadIdx.x >> 5;   // 32 x 8
#pragma unroll
  for (int j = 0; j < 32; j += 8)
    tile[ty + j][tx] = src[(size_t)(by + ty + j) * Nc + bx + tx];
  __syncthreads();
#pragma unroll
  for (int j = 0; j < 32; j += 8)
    dst[(size_t)(bx + ty + j) * K + by + tx] = f2bfu(tile[tx][ty + j]);
}

// ---------------------------------------------------------------- bias pack
__global__ __launch_bounds__(256) void k_pack_bias(
    const float* __restrict__ bq, const float* __restrict__ bk,
    const float* __restrict__ bv, float* __restrict__ dst) {
  int i = blockIdx.x * 256 + threadIdx.x;
  if (i < 3 * CH)
    dst[i] = i < CH ? bq[i] : (i < 2 * CH ? bk[i - CH] : bv[i - 2 * CH]);
}

// ---------------------------------------------------------------- layernorm
__global__ __launch_bounds__(256) void k_layernorm_bf16(
    const float* __restrict__ src, const float* __restrict__ gamma,
    const float* __restrict__ beta, u16* __restrict__ dst) {
  int row  = blockIdx.x * 4 + (threadIdx.x >> 6);
  int lane = threadIdx.x & 63;
  const float4* p4 = (const float4*)(src + (size_t)row * CH);
  float4 v[3];
  float s = 0.f, s2 = 0.f;
#pragma unroll
  for (int k = 0; k < 3; k++) {
    v[k] = p4[lane + k * 64];
    s  += v[k].x + v[k].y + v[k].z + v[k].w;
    s2 += v[k].x * v[k].x + v[k].y * v[k].y + v[k].z * v[k].z + v[k].w * v[k].w;
  }
#pragma unroll
  for (int m = 1; m < 64; m <<= 1) {
    s  += __shfl_xor(s,  m, 64);
    s2 += __shfl_xor(s2, m, 64);
  }
  float mean = s * (1.f / CH);
  float var  = s2 * (1.f / CH) - mean * mean;
  float rs   = rsqrtf(var + 1e-5f);
  u16* drow = dst + (size_t)row * CH;
#pragma unroll
  for (int k = 0; k < 3; k++) {
    int col = lane * 4 + k * 256;
    float4 gq = ((const float4*)gamma)[lane + k * 64];
    float4 bq = ((const float4*)beta )[lane + k * 64];
    u32 lo = (u32)f2bfu((v[k].x - mean) * rs * gq.x + bq.x) |
             ((u32)f2bfu((v[k].y - mean) * rs * gq.y + bq.y) << 16);
    u32 hi = (u32)f2bfu((v[k].z - mean) * rs * gq.z + bq.z) |
             ((u32)f2bfu((v[k].w - mean) * rs * gq.w + bq.w) << 16);
    uint2 w; w.x = lo; w.y = hi;
    *(uint2*)(drow + col) = w;
  }
}

enum { EPI_QKV = 0, EPI_RESID = 1, EPI_RELU = 2 };

// ------------------------------------------------- shared epilogue (16x16)
// D row = (lane>>4)*4 + r, col = lane&15 (m89-verified mapping). row0 % 4 == 0.
template <int EPI>
__device__ __forceinline__ void gemm_epi(const f32x4& a, int row0, int col,
                                         float bval, const float* resid,
                                         void* outp, int Nmat) {
  if constexpr (EPI == EPI_QKV) {
    int sel = col / CH;     // 256-col tiles align with CH=768 (768%256==0)
    int c = col - sel * CH;
    int h = c >> 6, d = c & 63;
    int bb = row0 >> 10, nn0 = row0 & (SEQ - 1);
    if (sel == 2) {
      // V stored TRANSPOSED per head: [B*H][DH][N]; 4 consecutive token rows
      union { uint2 u; u16 h4[4]; } pk;
#pragma unroll
      for (int r = 0; r < 4; r++) pk.h4[r] = f2bfu(a[r] + bval);
      *(uint2*)&((u16*)outp)[(size_t)2 * MR * CH +
                             (((size_t)(bb * NHD + h)) * DHD + d) * SEQ + nn0] =
          pk.u;
    } else {
#pragma unroll
      for (int r = 0; r < 4; r++)
        ((u16*)outp)[(size_t)sel * MR * CH +
                     (((size_t)(bb * NHD + h)) * SEQ + nn0 + r) * DHD + d] =
            f2bfu(a[r] + bval);
    }
  } else if constexpr (EPI == EPI_RESID) {
#pragma unroll
    for (int r = 0; r < 4; r++) {
      size_t idx = (size_t)(row0 + r) * Nmat + col;
      ((float*)outp)[idx] = a[r] + bval + resid[idx];
    }
  } else {  // RELU -> bf16 row-major
#pragma unroll
    for (int r = 0; r < 4; r++) {
      float val = a[r] + bval;
      ((u16*)outp)[(size_t)(row0 + r) * Nmat + col] =
          f2bfu(val > 0.f ? val : 0.f);
    }
  }
}

// ---------------------------------------------------------------- GEMM 8-phase
// m201-family template fitted to M=8192 x N in {768,2304,3072}:
// BM=128, BN=256, BK=64, 512 thr / 8 waves (2m x 4n), per-wave 64x64.
// 3-slot LDS ring (144KB, 1 block/CU, 2 waves/SIMD -- m201 regime).
// Per K-tile: 2 phases (ks-halves), each {ds_read 8x b128 | stage glds |
// setprio MFMA x16}; stages run 2 K-tiles ahead into the slot freed at kt-1;
// COUNTED vmcnt(6) at each K-tile boundary (6 = next tile's 6 glds in
// flight), vmcnt(0) only at the final tile. Ledger:
//   entering kt: outstanding = kt(6, issued @kt-2) + kt+1(6, @kt-1) = 12
//   vmcnt(6) -> kt resident, kt+1 in flight. Phases issue kt+2's 4+2.
// Slot-reuse safety: slot(kt+2)==slot(kt-1), whose reads finished before the
// boundary barrier. LDS 8x16B-slot XOR swizzle slot^=(row&7) on pre-swizzled
// global source (dest linear, rule #21) + reads -> 2-way, free.
template <int EPI>
__global__ __launch_bounds__(512, 2) void k_gemm8(
    const u16* __restrict__ A, const u16* __restrict__ Bt,
    const float* __restrict__ bias, const float* __restrict__ resid,
    void* __restrict__ outp, int K, int Nmat) {
  __shared__ u16 AL[3][128 * 64];   // 48 KB
  __shared__ u16 BL[3][256 * 64];   // 96 KB
  int tid = threadIdx.x;
  int bm = blockIdx.x, bn = blockIdx.y;
  int lane = tid & 63, wid = tid >> 6;
  int wm = wid >> 2, wn = wid & 3;          // 2x4 wave grid, wave tile 64x64
  int lrow = lane & 15, g = lane >> 4;

  const u16* Abase = A + (size_t)(bm * 128) * K;
  const u16* Bbase = Bt + (size_t)(bn * 256) * K;

  // stage one 16B unit: u in [0,1024) for A (128 rows x 8 slots),
  // [0,2048) for B (256 rows x 8 slots). dest = base + u*16B (lane-linear ✓).
  auto stA = [&](int s, int kt, int r) {
    int u = tid + r * 512;
    int row = u >> 3, slot = u & 7;
    glds16(Abase + (size_t)row * K + (kt << 6) + (((slot ^ (row & 7))) << 3),
           &AL[s][u * 8]);
  };
  auto stB = [&](int s, int kt, int r) {
    int u = tid + r * 512;
    int row = u >> 3, slot = u & 7;
    glds16(Bbase + (size_t)row * K + (kt << 6) + (((slot ^ (row & 7))) << 3),
           &BL[s][u * 8]);
  };

  int arow = wm * 64 + lrow;                // + mi*16
  int brow = wn * 64 + lrow;                // + n*16
  int swz = lrow & 7;
  int x0 = ((g) ^ swz) * 8;                 // ks=0 slot (u16 offset)
  int x1 = ((4 + g) ^ swz) * 8;             // ks=1 slot

  f32x4 acc[4][4];
#pragma unroll
  for (int m = 0; m < 4; m++)
#pragma unroll
    for (int n = 0; n < 4; n++) acc[m][n] = {0.f, 0.f, 0.f, 0.f};

  int NK = K >> 6;
  // prologue: stage K-tiles 0,1 (6 loads each; order matters for the ledger)
#pragma unroll
  for (int r = 0; r < 2; r++) stA(0, 0, r);
#pragma unroll
  for (int r = 0; r < 4; r++) stB(0, 0, r);
#pragma unroll
  for (int r = 0; r < 2; r++) stA(1, 1, r);
#pragma unroll
  for (int r = 0; r < 4; r++) stB(1, 1, r);

  for (int kt = 0; kt < NK; ++kt) {
    int s = kt % 3, sn = (kt + 2) % 3;
    bool pre = (kt + 2) < NK;
    if (kt < NK - 1) asm volatile("s_waitcnt vmcnt(6)" ::: "memory");
    else             asm volatile("s_waitcnt vmcnt(0)" ::: "memory");
    __builtin_amdgcn_s_barrier();
    __builtin_amdgcn_sched_barrier(0);

    // ---- phase 0 (ks = 0) ----
    if (pre) { stA(sn, kt + 2, 0); stA(sn, kt + 2, 1);
               stB(sn, kt + 2, 0); stB(sn, kt + 2, 1); }
    {
      bf16x8 af[4], bf[4];
#pragma unroll
      for (int mi = 0; mi < 4; mi++)
        af[mi] = *(const bf16x8*)&AL[s][(arow + mi * 16) * 64 + x0];
#pragma unroll
      for (int n = 0; n < 4; n++)
        bf[n] = *(const bf16x8*)&BL[s][(brow + n * 16) * 64 + x0];
      __builtin_amdgcn_s_setprio(1);
#pragma unroll
      for (int mi = 0; mi < 4; mi++)
#pragma unroll
        for (int n = 0; n < 4; n++)
          acc[mi][n] = __builtin_amdgcn_mfma_f32_16x16x32_bf16(
              af[mi], bf[n], acc[mi][n], 0, 0, 0);
      __builtin_amdgcn_s_setprio(0);
    }
    __builtin_amdgcn_s_barrier();
    __builtin_amdgcn_sched_barrier(0);

    // ---- phase 1 (ks = 1) ----
    if (pre) { stB(sn, kt + 2, 2); stB(sn, kt + 2, 3); }
    {
      bf16x8 af[4], bf[4];
#pragma unroll
      for (int mi = 0; mi < 4; mi++)
        af[mi] = *(const bf16x8*)&AL[s][(arow + mi * 16) * 64 + x1];
#pragma unroll
      for (int n = 0; n < 4; n++)
        bf[n] = *(const bf16x8*)&BL[s][(brow + n * 16) * 64 + x1];
      __builtin_amdgcn_s_setprio(1);
#pragma unroll
      for (int mi = 0; mi < 4; mi++)
#pragma unroll
        for (int n = 0; n < 4; n++)
          acc[mi][n] = __builtin_amdgcn_mfma_f32_16x16x32_bf16(
              af[mi], bf[n], acc[mi][n], 0, 0, 0);
      __builtin_amdgcn_s_setprio(0);
    }
    // K-tile boundary barrier is at the top of the next iteration
  }

#pragma unroll
  for (int mi = 0; mi < 4; mi++) {
    int row0 = bm * 128 + wm * 64 + mi * 16 + g * 4;
#pragma unroll
    for (int n = 0; n < 4; n++) {
      int col = bn * 256 + wn * 64 + n * 16 + lrow;
      gemm_epi<EPI>(acc[mi][n], row0, col, bias[col], resid, outp, Nmat);
    }
  }
}

// ---------------------------------------------------------------- attention
// (unchanged from round 8) flash-style, SWAPPED QK^T, glds-staged swizzled
// K / V^T tiles, defer-max (T13), 8 waves x 16 q-rows, bijective XCD swizzle.
__global__ __launch_bounds__(512, 4) void k_attn(
    const u16* __restrict__ Q, const u16* __restrict__ Kk,
    const u16* __restrict__ Vt, u16* __restrict__ Z) {
  __shared__ u16 Ks[2][64 * 64];
  __shared__ u16 Vs[2][64 * 64];     // V^T tile: [d][kv]
  __shared__ u32 Psu[8][64 * 9];     // per-wave P repack: [lane][2n+hi]
  int tid = threadIdx.x, lane = tid & 63, wid = tid >> 6;
  int lrow = lane & 15, g = lane >> 4;
  int id  = blockIdx.x;
  int nid = (id & 7) * 96 + (id >> 3);
  int bh = nid >> 3;
  int qtile = (nid & 7) * 128;
  size_t base = (size_t)bh * SEQ * DHD;
  int bb = bh / NHD, hh = bh % NHD;
  int qrow0 = qtile + wid * 16;

  bf16x8 qf[2];
#pragma unroll
  for (int ks = 0; ks < 2; ks++)
    qf[ks] = *(const bf16x8*)(Q + base + (size_t)(qrow0 + lrow) * DHD +
                              ks * 32 + g * 8);

  f32x4 accO[4];
  float mrun = -1e30f, lrun = 0.f;
#pragma unroll
  for (int n = 0; n < 4; n++) accO[n] = {0.f, 0.f, 0.f, 0.f};

  int srow = tid >> 3;
  int swz  = (((tid & 7) * 16) ^ ((srow & 7) << 4)) >> 1;   // u16 units
  const u16* kg0 = Kk + base + (size_t)srow * DHD + swz;
  const u16* vg0 = Vt + base + (size_t)srow * SEQ + swz;

  auto stageKV = [&](int buf, int t) {
    glds16(kg0 + (size_t)t * 64 * DHD, &Ks[buf][tid * 8]);
    glds16(vg0 + t * 64,               &Vs[buf][tid * 8]);
  };

  int rc0 = ((g * 16)      ^ ((lrow & 7) << 4)) >> 1;
  int rc1 = ((64 + g * 16) ^ ((lrow & 7) << 4)) >> 1;

  stageKV(0, 0);
  for (int t = 0; t < 16; ++t) {
    int buf = t & 1;
    __syncthreads();
    if (t + 1 < 16) stageKV(buf ^ 1, t + 1);

    f32x4 sacc[4];
    __builtin_amdgcn_s_setprio(1);
#pragma unroll
    for (int n = 0; n < 4; n++) {
      bf16x8 kf0 = *(const bf16x8*)&Ks[buf][(n * 16 + lrow) * 64 + rc0];
      bf16x8 kf1 = *(const bf16x8*)&Ks[buf][(n * 16 + lrow) * 64 + rc1];
      sacc[n] = {0.f, 0.f, 0.f, 0.f};
      sacc[n] = __builtin_amdgcn_mfma_f32_16x16x32_bf16(kf0, qf[0], sacc[n], 0, 0, 0);
      sacc[n] = __builtin_amdgcn_mfma_f32_16x16x32_bf16(kf1, qf[1], sacc[n], 0, 0, 0);
    }
    __builtin_amdgcn_s_setprio(0);

    float mx = fmaxf(fmaxf(fmaxf(sacc[0][0], sacc[0][1]),
                           fmaxf(sacc[0][2], sacc[0][3])),
                     fmaxf(fmaxf(sacc[1][0], sacc[1][1]),
                           fmaxf(sacc[1][2], sacc[1][3])));
    mx = fmaxf(mx, fmaxf(fmaxf(fmaxf(sacc[2][0], sacc[2][1]),
                               fmaxf(sacc[2][2], sacc[2][3])),
                         fmaxf(fmaxf(sacc[3][0], sacc[3][1]),
                               fmaxf(sacc[3][2], sacc[3][3]))));
    mx *= 0.125f;
    mx = fmaxf(mx, __shfl_xor(mx, 16, 64));
    mx = fmaxf(mx, __shfl_xor(mx, 32, 64));

    if (__all(mx <= mrun + 8.f)) {
      float psum = 0.f;
#pragma unroll
      for (int n = 0; n < 4; n++)
#pragma unroll
        for (int r = 0; r < 4; r++) {
          float p = __expf(sacc[n][r] * 0.125f - mrun);
          sacc[n][r] = p;
          psum += p;
        }
      psum += __shfl_xor(psum, 16, 64);
      psum += __shfl_xor(psum, 32, 64);
      lrun += psum;
    } else {
      float mnew = fmaxf(mrun, mx);
      float alpha = __expf(mrun - mnew);
      float psum = 0.f;
#pragma unroll
      for (int n = 0; n < 4; n++)
#pragma unroll
        for (int r = 0; r < 4; r++) {
          float p = __expf(sacc[n][r] * 0.125f - mnew);
          sacc[n][r] = p;
          psum += p;
        }
      psum += __shfl_xor(psum, 16, 64);
      psum += __shfl_xor(psum, 32, 64);
      lrun = lrun * alpha + psum;
      mrun = mnew;
#pragma unroll
      for (int r = 0; r < 4; r++) {
        float ar = __shfl(alpha, (lane & 48) | (g * 4 + r), 64);
#pragma unroll
        for (int n = 0; n < 4; n++) accO[n][r] *= ar;
      }
    }

#pragma unroll
    for (int n = 0; n < 4; n++) {
      u32 lo = (u32)f2bfu(sacc[n][0]) | ((u32)f2bfu(sacc[n][1]) << 16);
      u32 hi = (u32)f2bfu(sacc[n][2]) | ((u32)f2bfu(sacc[n][3]) << 16);
      Psu[wid][lane * 9 + 2 * n]     = lo;
      Psu[wid][lane * 9 + 2 * n + 1] = hi;
    }

    int laneA = lrow + ((g & 1) << 5);
    int laneB = laneA + 16;
    int nsel = g >> 1;
    __builtin_amdgcn_s_setprio(1);
#pragma unroll
    for (int ks = 0; ks < 2; ks++) {
      int nks = 2 * ks + nsel;
      union { bf16x8 v; u32 w[4]; } pk;
      pk.w[0] = Psu[wid][laneA * 9 + 2 * nks];
      pk.w[1] = Psu[wid][laneA * 9 + 2 * nks + 1];
      pk.w[2] = Psu[wid][laneB * 9 + 2 * nks];
      pk.w[3] = Psu[wid][laneB * 9 + 2 * nks + 1];
      int rc = ks ? rc1 : rc0;
#pragma unroll
      for (int n = 0; n < 4; n++) {
        bf16x8 vf = *(const bf16x8*)&Vs[buf][(n * 16 + lrow) * 64 + rc];
        accO[n] = __builtin_amdgcn_mfma_f32_16x16x32_bf16(pk.v, vf,
                                                          accO[n], 0, 0, 0);
      }
    }
    __builtin_amdgcn_s_setprio(0);
  }

#pragma unroll
  for (int r = 0; r < 4; r++) {
    float lr = __shfl(lrun, (lane & 48) | (g * 4 + r), 64);
    float inv = 1.f / lr;
    int qrow = qrow0 + g * 4 + r;
#pragma unroll
    for (int n = 0; n < 4; n++) {
      int d = n * 16 + lrow;
      Z[((size_t)(bb * SEQ + qrow)) * CH + hh * DHD + d] =
          f2bfu(accO[n][r] * inv);
    }
  }
}

// ---------------------------------------------------------------- launch
extern "C" void kernel_launch(void* const* d_in, const int* in_sizes, int n_in,
                              void* d_out, int out_size, void* d_ws,
                              size_t ws_size, hipStream_t stream) {
  (void)in_sizes; (void)n_in; (void)out_size; (void)ws_size;
  const float* x   = (const float*)d_in[0];
  const float* Wq  = (const float*)d_in[1];
  const float* bq  = (const float*)d_in[2];
  const float* Wk  = (const float*)d_in[3];
  const float* bk  = (const float*)d_in[4];
  const float* Wv  = (const float*)d_in[5];
  const float* bv  = (const float*)d_in[6];
  const float* Wo  = (const float*)d_in[7];
  const float* bo  = (const float*)d_in[8];
  const float* g1  = (const float*)d_in[9];
  const float* b1  = (const float*)d_in[10];
  const float* g2  = (const float*)d_in[11];
  const float* b2  = (const float*)d_in[12];
  const float* W1  = (const float*)d_in[13];
  const float* bf1 = (const float*)d_in[14];
  const float* W2  = (const float*)d_in[15];
  const float* bf2 = (const float*)d_in[16];

  u16* wsu  = (u16*)d_ws;
  u16* wq_t = wsu;                               // [3C][C] packed q,k,v
  u16* wo_t = wq_t + (size_t)3 * CH * CH;
  u16* w1_t = wo_t + (size_t)CH * CH;            // [FF][C]
  u16* w2_t = w1_t + (size_t)CH * FFD;           // [C][FF]
  u16* xn   = w2_t + (size_t)CH * FFD;           // [M][C]
  u16* qb   = xn + (size_t)MR * CH;              // q,k: [B*H][N][DH]; v: [B*H][DH][N]
  u16* zb   = qb + (size_t)3 * MR * CH;          // [B][N][C]
  float* bres = (float*)(zb + (size_t)MR * CH);  // [M][C] fp32
  u16* hb   = qb;                                // reuse region: [M][FF]
  float* bqkv = (float*)d_out;                   // packed bias (overwritten)

  dim3 blk(256);
  k_transpose_all<<<6912, blk, 0, stream>>>(Wq, Wk, Wv, Wo, W1, W2, wsu);
  k_pack_bias<<<9, blk, 0, stream>>>(bq, bk, bv, bqkv);

  k_layernorm_bf16<<<2048, blk, 0, stream>>>(x, g1, b1, xn);
  k_gemm8<EPI_QKV><<<dim3(64, 9), dim3(512), 0, stream>>>(
      xn, wq_t, bqkv, nullptr, qb, CH, 3 * CH);
  k_attn<<<768, dim3(512), 0, stream>>>(qb, qb + (size_t)MR * CH,
                                        qb + (size_t)2 * MR * CH, zb);
  k_gemm8<EPI_RESID><<<dim3(64, 3), dim3(512), 0, stream>>>(
      zb, wo_t, bo, x, bres, CH, CH);
  k_layernorm_bf16<<<2048, blk, 0, stream>>>(bres, g2, b2, xn);
  k_gemm8<EPI_RELU><<<dim3(64, 12), dim3(512), 0, stream>>>(
      xn, w1_t, bf1, nullptr, hb, CH, FFD);
  k_gemm8<EPI_RESID><<<dim3(64, 3), dim3(512), 0, stream>>>(
      hb, w2_t, bf2, bres, (float*)d_out, FFD, CH);
}

// Round 11
// 248.614 us; speedup vs baseline: 1.2798x; 1.2798x over previous
//
#include <hip/hip_runtime.h>
#include <hip/hip_bf16.h>

// ViT encoder block: B=8, N=1024, C=768, H=12, DH=64, FF=3072, fp32 in/out,
// bf16 MFMA compute internally.
#define BDIM 8
#define SEQ  1024
#define CH   768
#define NHD  12
#define DHD  64
#define FFD  3072
#define MR   (BDIM*SEQ)   // 8192 token rows

typedef __attribute__((ext_vector_type(8))) short bf16x8;
typedef __attribute__((ext_vector_type(4))) float f32x4;
typedef unsigned int   u32;
typedef unsigned short u16;

__device__ __forceinline__ u16 f2bfu(float x) {
  __hip_bfloat16 h = __float2bfloat16(x);
  return *reinterpret_cast<u16*>(&h);
}

__device__ __forceinline__ void glds16(const void* g, void* l) {
  __builtin_amdgcn_global_load_lds(
      (const __attribute__((address_space(1))) u32*)g,
      (__attribute__((address_space(3))) u32*)l, 16, 0, 0);
}

// ---------------------------------------------------------------- transpose
// All 6 weights + bias pack in one launch. W [K][Nc] fp32 -> Wt [Nc][K] bf16.
// Blocks >= 6912 pack bq|bk|bv into bdst (float[2304]).
__global__ __launch_bounds__(256) void k_transpose_all(
    const float* __restrict__ Wq, const float* __restrict__ Wk,
    const float* __restrict__ Wv, const float* __restrict__ Wo,
    const float* __restrict__ W1, const float* __restrict__ W2,
    u16* __restrict__ ws, const float* __restrict__ bq,
    const float* __restrict__ bk, const float* __restrict__ bv,
    float* __restrict__ bdst) {
  __shared__ float tile[32][33];
  int b = blockIdx.x;
  if (b >= 6912) {
    int i = (b - 6912) * 256 + threadIdx.x;
    if (i < 3 * CH)
      bdst[i] = i < CH ? bq[i] : (i < 2 * CH ? bk[i - CH] : bv[i - 2 * CH]);
    return;
  }
  int id, tb;
  if (b < 2304)      { id = b / 576; tb = b % 576; }
  else if (b < 4608) { id = 4;       tb = b - 2304; }
  else               { id = 5;       tb = b - 4608; }
  const float* src;
  u16* dst;
  int K, Nc;
  switch (id) {
    case 0: src = Wq; dst = ws;                      K = CH;  Nc = CH;  break;
    case 1: src = Wk; dst = ws + (size_t)CH*CH;      K = CH;  Nc = CH;  break;
    case 2: src = Wv; dst = ws + (size_t)2*CH*CH;    K = CH;  Nc = CH;  break;
    case 3: src = Wo; dst = ws + (size_t)3*CH*CH;    K = CH;  Nc = CH;  break;
    case 4: src = W1; dst = ws + (size_t)4*CH*CH;    K = CH;  Nc = FFD; break;
    default:src = W2; dst = ws + (size_t)4*CH*CH + (size_t)CH*FFD;
                                                     K = FFD; Nc = CH;  break;
  }
  int tilesx = Nc >> 5;
  int bx = (tb % tilesx) * 32;        // Nc dim
  int by = (tb / tilesx) * 32;        // K dim
  int tx = threadIdx.x & 31, ty = threadIdx.x >> 5;   // 32 x 8
#pragma unroll
  for (int j = 0; j < 32; j += 8)
    tile[ty + j][tx] = src[(size_t)(by + ty + j) * Nc + bx + tx];
  __syncthreads();
#pragma unroll
  for (int j = 0; j < 32; j += 8)
    dst[(size_t)(bx + ty + j) * K + by + tx] = f2bfu(tile[tx][ty + j]);
}

// ---------------------------------------------------------------- layernorm
__global__ __launch_bounds__(256) void k_layernorm_bf16(
    const float* __restrict__ src, const float* __restrict__ gamma,
    const float* __restrict__ beta, u16* __restrict__ dst) {
  int row  = blockIdx.x * 4 + (threadIdx.x >> 6);
  int lane = threadIdx.x & 63;
  const float4* p4 = (const float4*)(src + (size_t)row * CH);
  float4 v[3];
  float s = 0.f, s2 = 0.f;
#pragma unroll
  for (int k = 0; k < 3; k++) {
    v[k] = p4[lane + k * 64];
    s  += v[k].x + v[k].y + v[k].z + v[k].w;
    s2 += v[k].x * v[k].x + v[k].y * v[k].y + v[k].z * v[k].z + v[k].w * v[k].w;
  }
#pragma unroll
  for (int m = 1; m < 64; m <<= 1) {
    s  += __shfl_xor(s,  m, 64);
    s2 += __shfl_xor(s2, m, 64);
  }
  float mean = s * (1.f / CH);
  float var  = s2 * (1.f / CH) - mean * mean;
  float rs   = rsqrtf(var + 1e-5f);
  u16* drow = dst + (size_t)row * CH;
#pragma unroll
  for (int k = 0; k < 3; k++) {
    int col = lane * 4 + k * 256;
    float4 gq = ((const float4*)gamma)[lane + k * 64];
    float4 bq = ((const float4*)beta )[lane + k * 64];
    u32 lo = (u32)f2bfu((v[k].x - mean) * rs * gq.x + bq.x) |
             ((u32)f2bfu((v[k].y - mean) * rs * gq.y + bq.y) << 16);
    u32 hi = (u32)f2bfu((v[k].z - mean) * rs * gq.z + bq.z) |
             ((u32)f2bfu((v[k].w - mean) * rs * gq.w + bq.w) << 16);
    uint2 w; w.x = lo; w.y = hi;
    *(uint2*)(drow + col) = w;
  }
}

enum { EPI_QKV = 0, EPI_RESID = 1, EPI_RELU = 2 };

// ------------------------------------------------- shared epilogue (16x16)
// D row = (lane>>4)*4 + r, col = lane&15 (m89-verified mapping). row0 % 4 == 0.
template <int EPI>
__device__ __forceinline__ void gemm_epi(const f32x4& a, int row0, int col,
                                         float bval, const float* resid,
                                         void* outp, int Nmat) {
  if constexpr (EPI == EPI_QKV) {
    int sel = col / CH;                       // 128-col tile is within one sel
    int c = col - sel * CH;
    int h = c >> 6, d = c & 63;
    int bb = row0 >> 10, nn0 = row0 & (SEQ - 1);
    if (sel == 2) {
      // V stored TRANSPOSED per head: [B*H][DH][N]; 4 consecutive token rows
      union { uint2 u; u16 h4[4]; } pk;
#pragma unroll
      for (int r = 0; r < 4; r++) pk.h4[r] = f2bfu(a[r] + bval);
      *(uint2*)&((u16*)outp)[(size_t)2 * MR * CH +
                             (((size_t)(bb * NHD + h)) * DHD + d) * SEQ + nn0] =
          pk.u;
    } else {
#pragma unroll
      for (int r = 0; r < 4; r++)
        ((u16*)outp)[(size_t)sel * MR * CH +
                     (((size_t)(bb * NHD + h)) * SEQ + nn0 + r) * DHD + d] =
            f2bfu(a[r] + bval);
    }
  } else if constexpr (EPI == EPI_RESID) {
#pragma unroll
    for (int r = 0; r < 4; r++) {
      size_t idx = (size_t)(row0 + r) * Nmat + col;
      ((float*)outp)[idx] = a[r] + bval + resid[idx];
    }
  } else {  // RELU -> bf16 row-major
#pragma unroll
    for (int r = 0; r < 4; r++) {
      float val = a[r] + bval;
      ((u16*)outp)[(size_t)(row0 + r) * Nmat + col] =
          f2bfu(val > 0.f ? val : 0.f);
    }
  }
}

// ---------------------------------------------------------------- GEMM 2ph
// Round-8 proven: TMx128 tile, BK=32, 4 waves, dbuf LDS, global_load_lds,
// T2 swizzle (conflicts=0), natural dispatch. QKV, Wo, W1.
template <int EPI, int TM = 128>
__global__ __launch_bounds__(256, 2) void k_gemm(
    const u16* __restrict__ A, const u16* __restrict__ Bt,
    const float* __restrict__ bias, const float* __restrict__ resid,
    void* __restrict__ outp, int K, int Nmat) {
  __shared__ u16 As[2][TM * 32];
  __shared__ u16 Bs[2][128 * 32];
  constexpr int MF = TM / 32;       // m-fragments per wave
  int tid = threadIdx.x;
  int bm = blockIdx.x, bn = blockIdx.y;
  int lane = tid & 63, wid = tid >> 6;
  int wr = (wid >> 1) * (TM / 2), wc = (wid & 1) * 64;
  int lrow = lane & 15, g = lane >> 4;

  const u16* Abase = A + (size_t)(bm * TM) * K;
  const u16* Bbase = Bt + (size_t)(bn * 128) * K;

  auto stage = [&](int buf, int k0) {
#pragma unroll
    for (int r = 0; r < TM / 64; r++) {
      int c = tid + r * 256;
      int row = c >> 2;
      int scol = ((c & 3) ^ ((row >> 1) & 3)) * 8;
      glds16(Abase + (size_t)row * K + k0 + scol, &As[buf][c * 8]);
    }
#pragma unroll
    for (int r = 0; r < 2; r++) {
      int c = tid + r * 256;
      int row = c >> 2;
      int scol = ((c & 3) ^ ((row >> 1) & 3)) * 8;
      glds16(Bbase + (size_t)row * K + k0 + scol, &Bs[buf][c * 8]);
    }
  };

  int xsl = (g ^ ((lrow >> 1) & 3)) * 8;

  f32x4 acc[MF][4];
#pragma unroll
  for (int m = 0; m < MF; m++)
#pragma unroll
    for (int n = 0; n < 4; n++) acc[m][n] = {0.f, 0.f, 0.f, 0.f};

  int nk = K >> 5;
  stage(0, 0);
  for (int kt = 0; kt < nk; ++kt) {
    int buf = kt & 1;
    __syncthreads();
    if (kt + 1 < nk) stage(buf ^ 1, (kt + 1) << 5);
    bf16x8 af[MF], bfr[4];
#pragma unroll
    for (int m = 0; m < MF; m++)
      af[m] = *(const bf16x8*)&As[buf][(wr + m * 16 + lrow) * 32 + xsl];
#pragma unroll
    for (int n = 0; n < 4; n++)
      bfr[n] = *(const bf16x8*)&Bs[buf][(wc + n * 16 + lrow) * 32 + xsl];
    __builtin_amdgcn_s_setprio(1);
#pragma unroll
    for (int m = 0; m < MF; m++)
#pragma unroll
      for (int n = 0; n < 4; n++)
        acc[m][n] = __builtin_amdgcn_mfma_f32_16x16x32_bf16(af[m], bfr[n],
                                                            acc[m][n], 0, 0, 0);
    __builtin_amdgcn_s_setprio(0);
  }

#pragma unroll
  for (int m = 0; m < MF; m++) {
    int row0 = bm * TM + wr + m * 16 + g * 4;
#pragma unroll
    for (int n = 0; n < 4; n++) {
      int col = bn * 128 + wc + n * 16 + lrow;
      gemm_epi<EPI>(acc[m][n], row0, col, bias[col], resid, outp, Nmat);
    }
  }
}

// ---------------------------------------------------------------- GEMM BK64
// W2 only (K=3072): TM=64, BN=128, BK=64 -> HALF the __syncthreads+drain
// count of the BK=32 path (48 vs 96), with identical per-64-K-col MFMA /
// ds_read / glds counts. Conflicts held at 0 by the row&7 XOR swizzle
// (read pattern measured conflict-free in round 10). LDS 48KB -> 3 blk/CU.
template <int EPI>
__global__ __launch_bounds__(256, 2) void k_gemmk64(
    const u16* __restrict__ A, const u16* __restrict__ Bt,
    const float* __restrict__ bias, const float* __restrict__ resid,
    void* __restrict__ outp, int K, int Nmat) {
  __shared__ u16 As[2][64 * 64];
  __shared__ u16 Bs[2][128 * 64];
  int tid = threadIdx.x;
  int bm = blockIdx.x, bn = blockIdx.y;
  int lane = tid & 63, wid = tid >> 6;
  int wr = (wid >> 1) * 32, wc = (wid & 1) * 64;
  int lrow = lane & 15, g = lane >> 4;

  const u16* Abase = A + (size_t)(bm * 64) * K;
  const u16* Bbase = Bt + (size_t)(bn * 128) * K;

  // stage: unit u = row*8 + phys_slot; source col = (phys^row&7) slot.
  auto stage = [&](int buf, int k0) {
#pragma unroll
    for (int r = 0; r < 2; r++) {               // A: 512 units
      int u = tid + r * 256;
      int row = u >> 3, slot = u & 7;
      glds16(Abase + (size_t)row * K + k0 + ((slot ^ (row & 7)) << 3),
             &As[buf][u * 8]);
    }
#pragma unroll
    for (int r = 0; r < 4; r++) {               // B: 1024 units
      int u = tid + r * 256;
      int row = u >> 3, slot = u & 7;
      glds16(Bbase + (size_t)row * K + k0 + ((slot ^ (row & 7)) << 3),
             &Bs[buf][u * 8]);
    }
  };

  int sx = lrow & 7;
  int x0 = (g ^ sx) * 8;            // ks=0: logical slot g
  int x1 = ((4 + g) ^ sx) * 8;      // ks=1: logical slot 4+g

  f32x4 acc[2][4];
#pragma unroll
  for (int m = 0; m < 2; m++)
#pragma unroll
    for (int n = 0; n < 4; n++) acc[m][n] = {0.f, 0.f, 0.f, 0.f};

  int nk = K >> 6;
  stage(0, 0);
  for (int kt = 0; kt < nk; ++kt) {
    int buf = kt & 1;
    __syncthreads();
    if (kt + 1 < nk) stage(buf ^ 1, (kt + 1) << 6);
#pragma unroll
    for (int ks = 0; ks < 2; ks++) {
      int xs = ks ? x1 : x0;
      bf16x8 af[2], bfr[4];
#pragma unroll
      for (int m = 0; m < 2; m++)
        af[m] = *(const bf16x8*)&As[buf][(wr + m * 16 + lrow) * 64 + xs];
#pragma unroll
      for (int n = 0; n < 4; n++)
        bfr[n] = *(const bf16x8*)&Bs[buf][(wc + n * 16 + lrow) * 64 + xs];
      __builtin_amdgcn_s_setprio(1);
#pragma unroll
      for (int m = 0; m < 2; m++)
#pragma unroll
        for (int n = 0; n < 4; n++)
          acc[m][n] = __builtin_amdgcn_mfma_f32_16x16x32_bf16(
              af[m], bfr[n], acc[m][n], 0, 0, 0);
      __builtin_amdgcn_s_setprio(0);
    }
  }

#pragma unroll
  for (int m = 0; m < 2; m++) {
    int row0 = bm * 64 + wr + m * 16 + g * 4;
#pragma unroll
    for (int n = 0; n < 4; n++) {
      int col = bn * 128 + wc + n * 16 + lrow;
      gemm_epi<EPI>(acc[m][n], row0, col, bias[col], resid, outp, Nmat);
    }
  }
}

// ---------------------------------------------------------------- attention
// (unchanged from round 8) flash-style, SWAPPED QK^T, glds-staged swizzled
// K / V^T tiles, defer-max (T13), 8 waves x 16 q-rows, bijective XCD swizzle.
__global__ __launch_bounds__(512, 4) void k_attn(
    const u16* __restrict__ Q, const u16* __restrict__ Kk,
    const u16* __restrict__ Vt, u16* __restrict__ Z) {
  __shared__ u16 Ks[2][64 * 64];
  __shared__ u16 Vs[2][64 * 64];     // V^T tile: [d][kv]
  __shared__ u32 Psu[8][64 * 9];     // per-wave P repack: [lane][2n+hi]
  int tid = threadIdx.x, lane = tid & 63, wid = tid >> 6;
  int lrow = lane & 15, g = lane >> 4;
  int id  = blockIdx.x;
  int nid = (id & 7) * 96 + (id >> 3);
  int bh = nid >> 3;
  int qtile = (nid & 7) * 128;
  size_t base = (size_t)bh * SEQ * DHD;
  int bb = bh / NHD, hh = bh % NHD;
  int qrow0 = qtile + wid * 16;

  bf16x8 qf[2];
#pragma unroll
  for (int ks = 0; ks < 2; ks++)
    qf[ks] = *(const bf16x8*)(Q + base + (size_t)(qrow0 + lrow) * DHD +
                              ks * 32 + g * 8);

  f32x4 accO[4];
  float mrun = -1e30f, lrun = 0.f;
#pragma unroll
  for (int n = 0; n < 4; n++) accO[n] = {0.f, 0.f, 0.f, 0.f};

  int srow = tid >> 3;
  int swz  = (((tid & 7) * 16) ^ ((srow & 7) << 4)) >> 1;   // u16 units
  const u16* kg0 = Kk + base + (size_t)srow * DHD + swz;
  const u16* vg0 = Vt + base + (size_t)srow * SEQ + swz;

  auto stageKV = [&](int buf, int t) {
    glds16(kg0 + (size_t)t * 64 * DHD, &Ks[buf][tid * 8]);
    glds16(vg0 + t * 64,               &Vs[buf][tid * 8]);
  };

  int rc0 = ((g * 16)      ^ ((lrow & 7) << 4)) >> 1;
  int rc1 = ((64 + g * 16) ^ ((lrow & 7) << 4)) >> 1;

  stageKV(0, 0);
  for (int t = 0; t < 16; ++t) {
    int buf = t & 1;
    __syncthreads();
    if (t + 1 < 16) stageKV(buf ^ 1, t + 1);

    f32x4 sacc[4];
    __builtin_amdgcn_s_setprio(1);
#pragma unroll
    for (int n = 0; n < 4; n++) {
      bf16x8 kf0 = *(const bf16x8*)&Ks[buf][(n * 16 + lrow) * 64 + rc0];
      bf16x8 kf1 = *(const bf16x8*)&Ks[buf][(n * 16 + lrow) * 64 + rc1];
      sacc[n] = {0.f, 0.f, 0.f, 0.f};
      sacc[n] = __builtin_amdgcn_mfma_f32_16x16x32_bf16(kf0, qf[0], sacc[n], 0, 0, 0);
      sacc[n] = __builtin_amdgcn_mfma_f32_16x16x32_bf16(kf1, qf[1], sacc[n], 0, 0, 0);
    }
    __builtin_amdgcn_s_setprio(0);

    float mx = fmaxf(fmaxf(fmaxf(sacc[0][0], sacc[0][1]),
                           fmaxf(sacc[0][2], sacc[0][3])),
                     fmaxf(fmaxf(sacc[1][0], sacc[1][1]),
                           fmaxf(sacc[1][2], sacc[1][3])));
    mx = fmaxf(mx, fmaxf(fmaxf(fmaxf(sacc[2][0], sacc[2][1]),
                               fmaxf(sacc[2][2], sacc[2][3])),
                         fmaxf(fmaxf(sacc[3][0], sacc[3][1]),
                               fmaxf(sacc[3][2], sacc[3][3]))));
    mx *= 0.125f;
    mx = fmaxf(mx, __shfl_xor(mx, 16, 64));
    mx = fmaxf(mx, __shfl_xor(mx, 32, 64));

    if (__all(mx <= mrun + 8.f)) {
      float psum = 0.f;
#pragma unroll
      for (int n = 0; n < 4; n++)
#pragma unroll
        for (int r = 0; r < 4; r++) {
          float p = __expf(sacc[n][r] * 0.125f - mrun);
          sacc[n][r] = p;
          psum += p;
        }
      psum += __shfl_xor(psum, 16, 64);
      psum += __shfl_xor(psum, 32, 64);
      lrun += psum;
    } else {
      float mnew = fmaxf(mrun, mx);
      float alpha = __expf(mrun - mnew);
      float psum = 0.f;
#pragma unroll
      for (int n = 0; n < 4; n++)
#pragma unroll
        for (int r = 0; r < 4; r++) {
          float p = __expf(sacc[n][r] * 0.125f - mnew);
          sacc[n][r] = p;
          psum += p;
        }
      psum += __shfl_xor(psum, 16, 64);
      psum += __shfl_xor(psum, 32, 64);
      lrun = lrun * alpha + psum;
      mrun = mnew;
#pragma unroll
      for (int r = 0; r < 4; r++) {
        float ar = __shfl(alpha, (lane & 48) | (g * 4 + r), 64);
#pragma unroll
        for (int n = 0; n < 4; n++) accO[n][r] *= ar;
      }
    }

#pragma unroll
    for (int n = 0; n < 4; n++) {
      u32 lo = (u32)f2bfu(sacc[n][0]) | ((u32)f2bfu(sacc[n][1]) << 16);
      u32 hi = (u32)f2bfu(sacc[n][2]) | ((u32)f2bfu(sacc[n][3]) << 16);
      Psu[wid][lane * 9 + 2 * n]     = lo;
      Psu[wid][lane * 9 + 2 * n + 1] = hi;
    }

    int laneA = lrow + ((g & 1) << 5);
    int laneB = laneA + 16;
    int nsel = g >> 1;
    __builtin_amdgcn_s_setprio(1);
#pragma unroll
    for (int ks = 0; ks < 2; ks++) {
      int nks = 2 * ks + nsel;
      union { bf16x8 v; u32 w[4]; } pk;
      pk.w[0] = Psu[wid][laneA * 9 + 2 * nks];
      pk.w[1] = Psu[wid][laneA * 9 + 2 * nks + 1];
      pk.w[2] = Psu[wid][laneB * 9 + 2 * nks];
      pk.w[3] = Psu[wid][laneB * 9 + 2 * nks + 1];
      int rc = ks ? rc1 : rc0;
#pragma unroll
      for (int n = 0; n < 4; n++) {
        bf16x8 vf = *(const bf16x8*)&Vs[buf][(n * 16 + lrow) * 64 + rc];
        accO[n] = __builtin_amdgcn_mfma_f32_16x16x32_bf16(pk.v, vf,
                                                          accO[n], 0, 0, 0);
      }
    }
    __builtin_amdgcn_s_setprio(0);
  }

#pragma unroll
  for (int r = 0; r < 4; r++) {
    float lr = __shfl(lrun, (lane & 48) | (g * 4 + r), 64);
    float inv = 1.f / lr;
    int qrow = qrow0 + g * 4 + r;
#pragma unroll
    for (int n = 0; n < 4; n++) {
      int d = n * 16 + lrow;
      Z[((size_t)(bb * SEQ + qrow)) * CH + hh * DHD + d] =
          f2bfu(accO[n][r] * inv);
    }
  }
}

// ---------------------------------------------------------------- launch
extern "C" void kernel_launch(void* const* d_in, const int* in_sizes, int n_in,
                              void* d_out, int out_size, void* d_ws,
                              size_t ws_size, hipStream_t stream) {
  (void)in_sizes; (void)n_in; (void)out_size; (void)ws_size;
  const float* x   = (const float*)d_in[0];
  const float* Wq  = (const float*)d_in[1];
  const float* bq  = (const float*)d_in[2];
  const float* Wk  = (const float*)d_in[3];
  const float* bk  = (const float*)d_in[4];
  const float* Wv  = (const float*)d_in[5];
  const float* bv  = (const float*)d_in[6];
  const float* Wo  = (const float*)d_in[7];
  const float* bo  = (const float*)d_in[8];
  const float* g1  = (const float*)d_in[9];
  const float* b1  = (const float*)d_in[10];
  const float* g2  = (const float*)d_in[11];
  const float* b2  = (const float*)d_in[12];
  const float* W1  = (const float*)d_in[13];
  const float* bf1 = (const float*)d_in[14];
  const float* W2  = (const float*)d_in[15];
  const float* bf2 = (const float*)d_in[16];

  u16* wsu  = (u16*)d_ws;
  u16* wq_t = wsu;                               // [3C][C] packed q,k,v
  u16* wo_t = wq_t + (size_t)3 * CH * CH;
  u16* w1_t = wo_t + (size_t)CH * CH;            // [FF][C]
  u16* w2_t = w1_t + (size_t)CH * FFD;           // [C][FF]
  u16* xn   = w2_t + (size_t)CH * FFD;           // [M][C]
  u16* qb   = xn + (size_t)MR * CH;              // q,k: [B*H][N][DH]; v: [B*H][DH][N]
  u16* zb   = qb + (size_t)3 * MR * CH;          // [B][N][C]
  float* bres = (float*)(zb + (size_t)MR * CH);  // [M][C] fp32
  u16* hb   = qb;                                // reuse region: [M][FF]
  float* bqkv = (float*)d_out;                   // packed bias (overwritten)

  dim3 blk(256);
  k_transpose_all<<<6921, blk, 0, stream>>>(Wq, Wk, Wv, Wo, W1, W2, wsu,
                                            bq, bk, bv, bqkv);

  k_layernorm_bf16<<<2048, blk, 0, stream>>>(x, g1, b1, xn);
  k_gemm<EPI_QKV, 128><<<dim3(64, 18), blk, 0, stream>>>(
      xn, wq_t, bqkv, nullptr, qb, CH, 3 * CH);
  k_attn<<<768, dim3(512), 0, stream>>>(qb, qb + (size_t)MR * CH,
                                        qb + (size_t)2 * MR * CH, zb);
  k_gemm<EPI_RESID, 64><<<dim3(128, 6), blk, 0, stream>>>(
      zb, wo_t, bo, x, bres, CH, CH);
  k_layernorm_bf16<<<2048, blk, 0, stream>>>(bres, g2, b2, xn);
  k_gemm<EPI_RELU, 128><<<dim3(64, 24), blk, 0, stream>>>(
      xn, w1_t, bf1, nullptr, hb, CH, FFD);
  k_gemmk64<EPI_RESID><<<dim3(128, 6), blk, 0, stream>>>(
      hb, w2_t, bf2, bres, (float*)d_out, FFD, CH);
}

// Round 12
// 244.443 us; speedup vs baseline: 1.3017x; 1.0171x over previous
//
#include <hip/hip_runtime.h>
#include <hip/hip_bf16.h>

// ViT encoder block: B=8, N=1024, C=768, H=12, DH=64, FF=3072, fp32 in/out,
// bf16 MFMA compute internally.
#define BDIM 8
#define SEQ  1024
#define CH   768
#define NHD  12
#define DHD  64
#define FFD  3072
#define MR   (BDIM*SEQ)   // 8192 token rows

typedef __attribute__((ext_vector_type(8))) short bf16x8;
typedef __attribute__((ext_vector_type(4))) float f32x4;
typedef unsigned int   u32;
typedef unsigned short u16;

__device__ __forceinline__ u16 f2bfu(float x) {
  __hip_bfloat16 h = __float2bfloat16(x);
  return *reinterpret_cast<u16*>(&h);
}

// pack two floats to bf16 pair (round-half-up): lo-word = a, hi-word = b
__device__ __forceinline__ u32 pk2(float a, float b) {
  u32 ua = __float_as_uint(a) + 0x8000u;
  u32 ub = __float_as_uint(b) + 0x8000u;
  return (ub & 0xFFFF0000u) | (ua >> 16);
}

__device__ __forceinline__ void glds16(const void* g, void* l) {
  __builtin_amdgcn_global_load_lds(
      (const __attribute__((address_space(1))) u32*)g,
      (__attribute__((address_space(3))) u32*)l, 16, 0, 0);
}

// ---------------------------------------------------------------- transpose
// All 6 weights + bias pack in one launch. W [K][Nc] fp32 -> Wt [Nc][K] bf16.
// Blocks >= 6912 pack bq|bk|bv into bdst (float[2304]).
__global__ __launch_bounds__(256) void k_transpose_all(
    const float* __restrict__ Wq, const float* __restrict__ Wk,
    const float* __restrict__ Wv, const float* __restrict__ Wo,
    const float* __restrict__ W1, const float* __restrict__ W2,
    u16* __restrict__ ws, const float* __restrict__ bq,
    const float* __restrict__ bk, const float* __restrict__ bv,
    float* __restrict__ bdst) {
  __shared__ float tile[32][33];
  int b = blockIdx.x;
  if (b >= 6912) {
    int i = (b - 6912) * 256 + threadIdx.x;
    if (i < 3 * CH)
      bdst[i] = i < CH ? bq[i] : (i < 2 * CH ? bk[i - CH] : bv[i - 2 * CH]);
    return;
  }
  int id, tb;
  if (b < 2304)      { id = b / 576; tb = b % 576; }
  else if (b < 4608) { id = 4;       tb = b - 2304; }
  else               { id = 5;       tb = b - 4608; }
  const float* src;
  u16* dst;
  int K, Nc;
  switch (id) {
    case 0: src = Wq; dst = ws;                      K = CH;  Nc = CH;  break;
    case 1: src = Wk; dst = ws + (size_t)CH*CH;      K = CH;  Nc = CH;  break;
    case 2: src = Wv; dst = ws + (size_t)2*CH*CH;    K = CH;  Nc = CH;  break;
    case 3: src = Wo; dst = ws + (size_t)3*CH*CH;    K = CH;  Nc = CH;  break;
    case 4: src = W1; dst = ws + (size_t)4*CH*CH;    K = CH;  Nc = FFD; break;
    default:src = W2; dst = ws + (size_t)4*CH*CH + (size_t)CH*FFD;
                                                     K = FFD; Nc = CH;  break;
  }
  int tilesx = Nc >> 5;
  int bx = (tb % tilesx) * 32;        // Nc dim
  int by = (tb / tilesx) * 32;        // K dim
  int tx = threadIdx.x & 31, ty = threadIdx.x >> 5;   // 32 x 8
#pragma unroll
  for (int j = 0; j < 32; j += 8)
    tile[ty + j][tx] = src[(size_t)(by + ty + j) * Nc + bx + tx];
  __syncthreads();
#pragma unroll
  for (int j = 0; j < 32; j += 8)
    dst[(size_t)(bx + ty + j) * K + by + tx] = f2bfu(tile[tx][ty + j]);
}

// ---------------------------------------------------------------- layernorm
__global__ __launch_bounds__(256) void k_layernorm_bf16(
    const float* __restrict__ src, const float* __restrict__ gamma,
    const float* __restrict__ beta, u16* __restrict__ dst) {
  int row  = blockIdx.x * 4 + (threadIdx.x >> 6);
  int lane = threadIdx.x & 63;
  const float4* p4 = (const float4*)(src + (size_t)row * CH);
  float4 v[3];
  float s = 0.f, s2 = 0.f;
#pragma unroll
  for (int k = 0; k < 3; k++) {
    v[k] = p4[lane + k * 64];
    s  += v[k].x + v[k].y + v[k].z + v[k].w;
    s2 += v[k].x * v[k].x + v[k].y * v[k].y + v[k].z * v[k].z + v[k].w * v[k].w;
  }
#pragma unroll
  for (int m = 1; m < 64; m <<= 1) {
    s  += __shfl_xor(s,  m, 64);
    s2 += __shfl_xor(s2, m, 64);
  }
  float mean = s * (1.f / CH);
  float var  = s2 * (1.f / CH) - mean * mean;
  float rs   = rsqrtf(var + 1e-5f);
  u16* drow = dst + (size_t)row * CH;
#pragma unroll
  for (int k = 0; k < 3; k++) {
    int col = lane * 4 + k * 256;
    float4 gq = ((const float4*)gamma)[lane + k * 64];
    float4 bq = ((const float4*)beta )[lane + k * 64];
    u32 lo = (u32)f2bfu((v[k].x - mean) * rs * gq.x + bq.x) |
             ((u32)f2bfu((v[k].y - mean) * rs * gq.y + bq.y) << 16);
    u32 hi = (u32)f2bfu((v[k].z - mean) * rs * gq.z + bq.z) |
             ((u32)f2bfu((v[k].w - mean) * rs * gq.w + bq.w) << 16);
    uint2 w; w.x = lo; w.y = hi;
    *(uint2*)(drow + col) = w;
  }
}

enum { EPI_QKV = 0, EPI_RESID = 1, EPI_RELU = 2 };

// ------------------------------------------------- shared epilogue (16x16)
// D row = (lane>>4)*4 + r, col = lane&15 (m89-verified mapping). row0 % 4 == 0.
template <int EPI>
__device__ __forceinline__ void gemm_epi(const f32x4& a, int row0, int col,
                                         float bval, const float* resid,
                                         void* outp, int Nmat) {
  if constexpr (EPI == EPI_QKV) {
    int sel = col / CH;                       // 128-col tile is within one sel
    int c = col - sel * CH;
    int h = c >> 6, d = c & 63;
    int bb = row0 >> 10, nn0 = row0 & (SEQ - 1);
    if (sel == 2) {
      // V stored TRANSPOSED per head: [B*H][DH][N]; 4 consecutive token rows
      union { uint2 u; u16 h4[4]; } pk;
#pragma unroll
      for (int r = 0; r < 4; r++) pk.h4[r] = f2bfu(a[r] + bval);
      *(uint2*)&((u16*)outp)[(size_t)2 * MR * CH +
                             (((size_t)(bb * NHD + h)) * DHD + d) * SEQ + nn0] =
          pk.u;
    } else {
#pragma unroll
      for (int r = 0; r < 4; r++)
        ((u16*)outp)[(size_t)sel * MR * CH +
                     (((size_t)(bb * NHD + h)) * SEQ + nn0 + r) * DHD + d] =
            f2bfu(a[r] + bval);
    }
  } else if constexpr (EPI == EPI_RESID) {
#pragma unroll
    for (int r = 0; r < 4; r++) {
      size_t idx = (size_t)(row0 + r) * Nmat + col;
      ((float*)outp)[idx] = a[r] + bval + resid[idx];
    }
  } else {  // RELU -> bf16 row-major
#pragma unroll
    for (int r = 0; r < 4; r++) {
      float val = a[r] + bval;
      ((u16*)outp)[(size_t)(row0 + r) * Nmat + col] =
          f2bfu(val > 0.f ? val : 0.f);
    }
  }
}

// ---------------------------------------------------------------- GEMM BK64
// Round-11 proven (W2 win): TM=64, BN=128, BK=64 -> half the barrier+drain
// count of BK=32 at identical per-64-K-col MFMA/ds/glds counts; conflicts
// held at 0 by the row&7 XOR swizzle on pre-swizzled global source (dest
// linear, rule #21) + reads. LDS 48KB -> 3 blk/CU. Natural dispatch.
// Now used for ALL four GEMMs.
template <int EPI>
__global__ __launch_bounds__(256, 2) void k_gemmk64(
    const u16* __restrict__ A, const u16* __restrict__ Bt,
    const float* __restrict__ bias, const float* __restrict__ resid,
    void* __restrict__ outp, int K, int Nmat) {
  __shared__ u16 As[2][64 * 64];
  __shared__ u16 Bs[2][128 * 64];
  int tid = threadIdx.x;
  int bm = blockIdx.x, bn = blockIdx.y;
  int lane = tid & 63, wid = tid >> 6;
  int wr = (wid >> 1) * 32, wc = (wid & 1) * 64;
  int lrow = lane & 15, g = lane >> 4;

  const u16* Abase = A + (size_t)(bm * 64) * K;
  const u16* Bbase = Bt + (size_t)(bn * 128) * K;

  // stage: unit u = row*8 + phys_slot; source col = (phys^row&7) slot.
  auto stage = [&](int buf, int k0) {
#pragma unroll
    for (int r = 0; r < 2; r++) {               // A: 512 units
      int u = tid + r * 256;
      int row = u >> 3, slot = u & 7;
      glds16(Abase + (size_t)row * K + k0 + ((slot ^ (row & 7)) << 3),
             &As[buf][u * 8]);
    }
#pragma unroll
    for (int r = 0; r < 4; r++) {               // B: 1024 units
      int u = tid + r * 256;
      int row = u >> 3, slot = u & 7;
      glds16(Bbase + (size_t)row * K + k0 + ((slot ^ (row & 7)) << 3),
             &Bs[buf][u * 8]);
    }
  };

  int sx = lrow & 7;
  int x0 = (g ^ sx) * 8;            // ks=0: logical slot g
  int x1 = ((4 + g) ^ sx) * 8;      // ks=1: logical slot 4+g

  f32x4 acc[2][4];
#pragma unroll
  for (int m = 0; m < 2; m++)
#pragma unroll
    for (int n = 0; n < 4; n++) acc[m][n] = {0.f, 0.f, 0.f, 0.f};

  int nk = K >> 6;
  stage(0, 0);
  for (int kt = 0; kt < nk; ++kt) {
    int buf = kt & 1;
    __syncthreads();
    if (kt + 1 < nk) stage(buf ^ 1, (kt + 1) << 6);
#pragma unroll
    for (int ks = 0; ks < 2; ks++) {
      int xs = ks ? x1 : x0;
      bf16x8 af[2], bfr[4];
#pragma unroll
      for (int m = 0; m < 2; m++)
        af[m] = *(const bf16x8*)&As[buf][(wr + m * 16 + lrow) * 64 + xs];
#pragma unroll
      for (int n = 0; n < 4; n++)
        bfr[n] = *(const bf16x8*)&Bs[buf][(wc + n * 16 + lrow) * 64 + xs];
      __builtin_amdgcn_s_setprio(1);
#pragma unroll
      for (int m = 0; m < 2; m++)
#pragma unroll
        for (int n = 0; n < 4; n++)
          acc[m][n] = __builtin_amdgcn_mfma_f32_16x16x32_bf16(
              af[m], bfr[n], acc[m][n], 0, 0, 0);
      __builtin_amdgcn_s_setprio(0);
    }
  }

#pragma unroll
  for (int m = 0; m < 2; m++) {
    int row0 = bm * 64 + wr + m * 16 + g * 4;
#pragma unroll
    for (int n = 0; n < 4; n++) {
      int col = bn * 128 + wc + n * 16 + lrow;
      gemm_epi<EPI>(acc[m][n], row0, col, bias[col], resid, outp, Nmat);
    }
  }
}

// ---------------------------------------------------------------- attention
// flash-style, SWAPPED QK^T, glds-staged swizzled K / V^T tiles, defer-max
// (T13), 8 waves x 16 q-rows, bijective XCD swizzle. Round-12: softmax in
// LOG2 domain (p = exp2(fma(s,S2,-m)) -- 1 fma + 1 v_exp vs 4 ops) and
// P-pack via round-half-up truncation pk2 (vs 2x RNE cvt) to cut VALU.
__global__ __launch_bounds__(512, 4) void k_attn(
    const u16* __restrict__ Q, const u16* __restrict__ Kk,
    const u16* __restrict__ Vt, u16* __restrict__ Z) {
  __shared__ u16 Ks[2][64 * 64];
  __shared__ u16 Vs[2][64 * 64];     // V^T tile: [d][kv]
  __shared__ u32 Psu[8][64 * 9];     // per-wave P repack: [lane][2n+hi]
  const float S2 = 0.18033688f;      // 0.125 * log2(e)
  int tid = threadIdx.x, lane = tid & 63, wid = tid >> 6;
  int lrow = lane & 15, g = lane >> 4;
  int id  = blockIdx.x;
  int nid = (id & 7) * 96 + (id >> 3);
  int bh = nid >> 3;
  int qtile = (nid & 7) * 128;
  size_t base = (size_t)bh * SEQ * DHD;
  int bb = bh / NHD, hh = bh % NHD;
  int qrow0 = qtile + wid * 16;

  bf16x8 qf[2];
#pragma unroll
  for (int ks = 0; ks < 2; ks++)
    qf[ks] = *(const bf16x8*)(Q + base + (size_t)(qrow0 + lrow) * DHD +
                              ks * 32 + g * 8);

  f32x4 accO[4];
  float mrun = -1e30f, lrun = 0.f;   // mrun in log2 units
#pragma unroll
  for (int n = 0; n < 4; n++) accO[n] = {0.f, 0.f, 0.f, 0.f};

  int srow = tid >> 3;
  int swz  = (((tid & 7) * 16) ^ ((srow & 7) << 4)) >> 1;   // u16 units
  const u16* kg0 = Kk + base + (size_t)srow * DHD + swz;
  const u16* vg0 = Vt + base + (size_t)srow * SEQ + swz;

  auto stageKV = [&](int buf, int t) {
    glds16(kg0 + (size_t)t * 64 * DHD, &Ks[buf][tid * 8]);
    glds16(vg0 + t * 64,               &Vs[buf][tid * 8]);
  };

  int rc0 = ((g * 16)      ^ ((lrow & 7) << 4)) >> 1;
  int rc1 = ((64 + g * 16) ^ ((lrow & 7) << 4)) >> 1;

  stageKV(0, 0);
  for (int t = 0; t < 16; ++t) {
    int buf = t & 1;
    __syncthreads();
    if (t + 1 < 16) stageKV(buf ^ 1, t + 1);

    f32x4 sacc[4];
    __builtin_amdgcn_s_setprio(1);
#pragma unroll
    for (int n = 0; n < 4; n++) {
      bf16x8 kf0 = *(const bf16x8*)&Ks[buf][(n * 16 + lrow) * 64 + rc0];
      bf16x8 kf1 = *(const bf16x8*)&Ks[buf][(n * 16 + lrow) * 64 + rc1];
      sacc[n] = {0.f, 0.f, 0.f, 0.f};
      sacc[n] = __builtin_amdgcn_mfma_f32_16x16x32_bf16(kf0, qf[0], sacc[n], 0, 0, 0);
      sacc[n] = __builtin_amdgcn_mfma_f32_16x16x32_bf16(kf1, qf[1], sacc[n], 0, 0, 0);
    }
    __builtin_amdgcn_s_setprio(0);

    float mx = fmaxf(fmaxf(fmaxf(sacc[0][0], sacc[0][1]),
                           fmaxf(sacc[0][2], sacc[0][3])),
                     fmaxf(fmaxf(sacc[1][0], sacc[1][1]),
                           fmaxf(sacc[1][2], sacc[1][3])));
    mx = fmaxf(mx, fmaxf(fmaxf(fmaxf(sacc[2][0], sacc[2][1]),
                               fmaxf(sacc[2][2], sacc[2][3])),
                         fmaxf(fmaxf(sacc[3][0], sacc[3][1]),
                               fmaxf(sacc[3][2], sacc[3][3]))));
    mx *= S2;                                   // log2 domain
    mx = fmaxf(mx, __shfl_xor(mx, 16, 64));
    mx = fmaxf(mx, __shfl_xor(mx, 32, 64));

    if (__all(mx <= mrun + 11.5f)) {            // 8 nats = 11.54 bits
      float psum = 0.f;
#pragma unroll
      for (int n = 0; n < 4; n++)
#pragma unroll
        for (int r = 0; r < 4; r++) {
          float p = exp2f(fmaf(sacc[n][r], S2, -mrun));
          sacc[n][r] = p;
          psum += p;
        }
      psum += __shfl_xor(psum, 16, 64);
      psum += __shfl_xor(psum, 32, 64);
      lrun += psum;
    } else {
      float mnew = fmaxf(mrun, mx);
      float alpha = exp2f(mrun - mnew);
      float psum = 0.f;
#pragma unroll
      for (int n = 0; n < 4; n++)
#pragma unroll
        for (int r = 0; r < 4; r++) {
          float p = exp2f(fmaf(sacc[n][r], S2, -mnew));
          sacc[n][r] = p;
          psum += p;
        }
      psum += __shfl_xor(psum, 16, 64);
      psum += __shfl_xor(psum, 32, 64);
      lrun = lrun * alpha + psum;
      mrun = mnew;
#pragma unroll
      for (int r = 0; r < 4; r++) {
        float ar = __shfl(alpha, (lane & 48) | (g * 4 + r), 64);
#pragma unroll
        for (int n = 0; n < 4; n++) accO[n][r] *= ar;
      }
    }

#pragma unroll
    for (int n = 0; n < 4; n++) {
      Psu[wid][lane * 9 + 2 * n]     = pk2(sacc[n][0], sacc[n][1]);
      Psu[wid][lane * 9 + 2 * n + 1] = pk2(sacc[n][2], sacc[n][3]);
    }

    int laneA = lrow + ((g & 1) << 5);
    int laneB = laneA + 16;
    int nsel = g >> 1;
    __builtin_amdgcn_s_setprio(1);
#pragma unroll
    for (int ks = 0; ks < 2; ks++) {
      int nks = 2 * ks + nsel;
      union { bf16x8 v; u32 w[4]; } pk;
      pk.w[0] = Psu[wid][laneA * 9 + 2 * nks];
      pk.w[1] = Psu[wid][laneA * 9 + 2 * nks + 1];
      pk.w[2] = Psu[wid][laneB * 9 + 2 * nks];
      pk.w[3] = Psu[wid][laneB * 9 + 2 * nks + 1];
      int rc = ks ? rc1 : rc0;
#pragma unroll
      for (int n = 0; n < 4; n++) {
        bf16x8 vf = *(const bf16x8*)&Vs[buf][(n * 16 + lrow) * 64 + rc];
        accO[n] = __builtin_amdgcn_mfma_f32_16x16x32_bf16(pk.v, vf,
                                                          accO[n], 0, 0, 0);
      }
    }
    __builtin_amdgcn_s_setprio(0);
  }

#pragma unroll
  for (int r = 0; r < 4; r++) {
    float lr = __shfl(lrun, (lane & 48) | (g * 4 + r), 64);
    float inv = 1.f / lr;
    int qrow = qrow0 + g * 4 + r;
#pragma unroll
    for (int n = 0; n < 4; n++) {
      int d = n * 16 + lrow;
      Z[((size_t)(bb * SEQ + qrow)) * CH + hh * DHD + d] =
          f2bfu(accO[n][r] * inv);
    }
  }
}

// ---------------------------------------------------------------- launch
extern "C" void kernel_launch(void* const* d_in, const int* in_sizes, int n_in,
                              void* d_out, int out_size, void* d_ws,
                              size_t ws_size, hipStream_t stream) {
  (void)in_sizes; (void)n_in; (void)out_size; (void)ws_size;
  const float* x   = (const float*)d_in[0];
  const float* Wq  = (const float*)d_in[1];
  const float* bq  = (const float*)d_in[2];
  const float* Wk  = (const float*)d_in[3];
  const float* bk  = (const float*)d_in[4];
  const float* Wv  = (const float*)d_in[5];
  const float* bv  = (const float*)d_in[6];
  const float* Wo  = (const float*)d_in[7];
  const float* bo  = (const float*)d_in[8];
  const float* g1  = (const float*)d_in[9];
  const float* b1  = (const float*)d_in[10];
  const float* g2  = (const float*)d_in[11];
  const float* b2  = (const float*)d_in[12];
  const float* W1  = (const float*)d_in[13];
  const float* bf1 = (const float*)d_in[14];
  const float* W2  = (const float*)d_in[15];
  const float* bf2 = (const float*)d_in[16];

  u16* wsu  = (u16*)d_ws;
  u16* wq_t = wsu;                               // [3C][C] packed q,k,v
  u16* wo_t = wq_t + (size_t)3 * CH * CH;
  u16* w1_t = wo_t + (size_t)CH * CH;            // [FF][C]
  u16* w2_t = w1_t + (size_t)CH * FFD;           // [C][FF]
  u16* xn   = w2_t + (size_t)CH * FFD;           // [M][C]
  u16* qb   = xn + (size_t)MR * CH;              // q,k: [B*H][N][DH]; v: [B*H][DH][N]
  u16* zb   = qb + (size_t)3 * MR * CH;          // [B][N][C]
  float* bres = (float*)(zb + (size_t)MR * CH);  // [M][C] fp32
  u16* hb   = qb;                                // reuse region: [M][FF]
  float* bqkv = (float*)d_out;                   // packed bias (overwritten)

  dim3 blk(256);
  k_transpose_all<<<6921, blk, 0, stream>>>(Wq, Wk, Wv, Wo, W1, W2, wsu,
                                            bq, bk, bv, bqkv);

  k_layernorm_bf16<<<2048, blk, 0, stream>>>(x, g1, b1, xn);
  k_gemmk64<EPI_QKV><<<dim3(128, 18), blk, 0, stream>>>(
      xn, wq_t, bqkv, nullptr, qb, CH, 3 * CH);
  k_attn<<<768, dim3(512), 0, stream>>>(qb, qb + (size_t)MR * CH,
                                        qb + (size_t)2 * MR * CH, zb);
  k_gemmk64<EPI_RESID><<<dim3(128, 6), blk, 0, stream>>>(
      zb, wo_t, bo, x, bres, CH, CH);
  k_layernorm_bf16<<<2048, blk, 0, stream>>>(bres, g2, b2, xn);
  k_gemmk64<EPI_RELU><<<dim3(128, 24), blk, 0, stream>>>(
      xn, w1_t, bf1, nullptr, hb, CH, FFD);
  k_gemmk64<EPI_RESID><<<dim3(128, 6), blk, 0, stream>>>(
      hb, w2_t, bf2, bres, (float*)d_out, FFD, CH);
}

// Round 13
// 237.170 us; speedup vs baseline: 1.3416x; 1.0307x over previous
//
#include <hip/hip_runtime.h>
#include <hip/hip_bf16.h>

// ViT encoder block: B=8, N=1024, C=768, H=12, DH=64, FF=3072, fp32 in/out,
// bf16 MFMA compute internally.
#define BDIM 8
#define SEQ  1024
#define CH   768
#define NHD  12
#define DHD  64
#define FFD  3072
#define MR   (BDIM*SEQ)   // 8192 token rows

typedef __attribute__((ext_vector_type(8))) short bf16x8;
typedef __attribute__((ext_vector_type(4))) float f32x4;
typedef unsigned int   u32;
typedef unsigned short u16;

__device__ __forceinline__ u16 f2bfu(float x) {
  __hip_bfloat16 h = __float2bfloat16(x);
  return *reinterpret_cast<u16*>(&h);
}

__device__ __forceinline__ void glds16(const void* g, void* l) {
  __builtin_amdgcn_global_load_lds(
      (const __attribute__((address_space(1))) u32*)g,
      (__attribute__((address_space(3))) u32*)l, 16, 0, 0);
}

// ---------------------------------------------------------------- transpose
// All 6 weights + bias pack in one launch. W [K][Nc] fp32 -> Wt [Nc][K] bf16.
// Blocks >= 6912 pack bq|bk|bv into bdst (float[2304]).
__global__ __launch_bounds__(256) void k_transpose_all(
    const float* __restrict__ Wq, const float* __restrict__ Wk,
    const float* __restrict__ Wv, const float* __restrict__ Wo,
    const float* __restrict__ W1, const float* __restrict__ W2,
    u16* __restrict__ ws, const float* __restrict__ bq,
    const float* __restrict__ bk, const float* __restrict__ bv,
    float* __restrict__ bdst) {
  __shared__ float tile[32][33];
  int b = blockIdx.x;
  if (b >= 6912) {
    int i = (b - 6912) * 256 + threadIdx.x;
    if (i < 3 * CH)
      bdst[i] = i < CH ? bq[i] : (i < 2 * CH ? bk[i - CH] : bv[i - 2 * CH]);
    return;
  }
  int id, tb;
  if (b < 2304)      { id = b / 576; tb = b % 576; }
  else if (b < 4608) { id = 4;       tb = b - 2304; }
  else               { id = 5;       tb = b - 4608; }
  const float* src;
  u16* dst;
  int K, Nc;
  switch (id) {
    case 0: src = Wq; dst = ws;                      K = CH;  Nc = CH;  break;
    case 1: src = Wk; dst = ws + (size_t)CH*CH;      K = CH;  Nc = CH;  break;
    case 2: src = Wv; dst = ws + (size_t)2*CH*CH;    K = CH;  Nc = CH;  break;
    case 3: src = Wo; dst = ws + (size_t)3*CH*CH;    K = CH;  Nc = CH;  break;
    case 4: src = W1; dst = ws + (size_t)4*CH*CH;    K = CH;  Nc = FFD; break;
    default:src = W2; dst = ws + (size_t)4*CH*CH + (size_t)CH*FFD;
                                                     K = FFD; Nc = CH;  break;
  }
  int tilesx = Nc >> 5;
  int bx = (tb % tilesx) * 32;        // Nc dim
  int by = (tb / tilesx) * 32;        // K dim
  int tx = threadIdx.x & 31, ty = threadIdx.x >> 5;   // 32 x 8
#pragma unroll
  for (int j = 0; j < 32; j += 8)
    tile[ty + j][tx] = src[(size_t)(by + ty + j) * Nc + bx + tx];
  __syncthreads();
#pragma unroll
  for (int j = 0; j < 32; j += 8)
    dst[(size_t)(bx + ty + j) * K + by + tx] = f2bfu(tile[tx][ty + j]);
}

// ---------------------------------------------------------------- layernorm
__global__ __launch_bounds__(256) void k_layernorm_bf16(
    const float* __restrict__ src, const float* __restrict__ gamma,
    const float* __restrict__ beta, u16* __restrict__ dst) {
  int row  = blockIdx.x * 4 + (threadIdx.x >> 6);
  int lane = threadIdx.x & 63;
  const float4* p4 = (const float4*)(src + (size_t)row * CH);
  float4 v[3];
  float s = 0.f, s2 = 0.f;
#pragma unroll
  for (int k = 0; k < 3; k++) {
    v[k] = p4[lane + k * 64];
    s  += v[k].x + v[k].y + v[k].z + v[k].w;
    s2 += v[k].x * v[k].x + v[k].y * v[k].y + v[k].z * v[k].z + v[k].w * v[k].w;
  }
#pragma unroll
  for (int m = 1; m < 64; m <<= 1) {
    s  += __shfl_xor(s,  m, 64);
    s2 += __shfl_xor(s2, m, 64);
  }
  float mean = s * (1.f / CH);
  float var  = s2 * (1.f / CH) - mean * mean;
  float rs   = rsqrtf(var + 1e-5f);
  u16* drow = dst + (size_t)row * CH;
#pragma unroll
  for (int k = 0; k < 3; k++) {
    int col = lane * 4 + k * 256;
    float4 gq = ((const float4*)gamma)[lane + k * 64];
    float4 bq = ((const float4*)beta )[lane + k * 64];
    u32 lo = (u32)f2bfu((v[k].x - mean) * rs * gq.x + bq.x) |
             ((u32)f2bfu((v[k].y - mean) * rs * gq.y + bq.y) << 16);
    u32 hi = (u32)f2bfu((v[k].z - mean) * rs * gq.z + bq.z) |
             ((u32)f2bfu((v[k].w - mean) * rs * gq.w + bq.w) << 16);
    uint2 w; w.x = lo; w.y = hi;
    *(uint2*)(drow + col) = w;
  }
}

enum { EPI_QKV = 0, EPI_RESID = 1, EPI_RELU = 2 };

// ------------------------------------------------- shared epilogue (16x16)
// D row = (lane>>4)*4 + r, col = lane&15 (m89-verified mapping). row0 % 4 == 0.
template <int EPI>
__device__ __forceinline__ void gemm_epi(const f32x4& a, int row0, int col,
                                         float bval, const float* resid,
                                         void* outp, int Nmat) {
  if constexpr (EPI == EPI_QKV) {
    int sel = col / CH;                       // 128-col tile is within one sel
    int c = col - sel * CH;
    int h = c >> 6, d = c & 63;
    int bb = row0 >> 10, nn0 = row0 & (SEQ - 1);
    if (sel == 2) {
      // V stored TRANSPOSED per head: [B*H][DH][N]; 4 consecutive token rows
      union { uint2 u; u16 h4[4]; } pk;
#pragma unroll
      for (int r = 0; r < 4; r++) pk.h4[r] = f2bfu(a[r] + bval);
      *(uint2*)&((u16*)outp)[(size_t)2 * MR * CH +
                             (((size_t)(bb * NHD + h)) * DHD + d) * SEQ + nn0] =
          pk.u;
    } else {
#pragma unroll
      for (int r = 0; r < 4; r++)
        ((u16*)outp)[(size_t)sel * MR * CH +
                     (((size_t)(bb * NHD + h)) * SEQ + nn0 + r) * DHD + d] =
            f2bfu(a[r] + bval);
    }
  } else if constexpr (EPI == EPI_RESID) {
#pragma unroll
    for (int r = 0; r < 4; r++) {
      size_t idx = (size_t)(row0 + r) * Nmat + col;
      ((float*)outp)[idx] = a[r] + bval + resid[idx];
    }
  } else {  // RELU -> bf16 row-major
#pragma unroll
    for (int r = 0; r < 4; r++) {
      float val = a[r] + bval;
      ((u16*)outp)[(size_t)(row0 + r) * Nmat + col] =
          f2bfu(val > 0.f ? val : 0.f);
    }
  }
}

// ---------------------------------------------------------------- GEMM BK64
// Round-11/12 proven: TM=64, BN=128, BK=64 -> half the barrier+drain count
// of BK=32 at identical per-64-K-col MFMA/ds/glds counts; conflicts held at
// 0 by the row&7 XOR swizzle on pre-swizzled global source (dest linear,
// rule #21) + reads. LDS 48KB -> 3 blk/CU. Natural dispatch. All four GEMMs.
template <int EPI>
__global__ __launch_bounds__(256, 2) void k_gemmk64(
    const u16* __restrict__ A, const u16* __restrict__ Bt,
    const float* __restrict__ bias, const float* __restrict__ resid,
    void* __restrict__ outp, int K, int Nmat) {
  __shared__ u16 As[2][64 * 64];
  __shared__ u16 Bs[2][128 * 64];
  int tid = threadIdx.x;
  int bm = blockIdx.x, bn = blockIdx.y;
  int lane = tid & 63, wid = tid >> 6;
  int wr = (wid >> 1) * 32, wc = (wid & 1) * 64;
  int lrow = lane & 15, g = lane >> 4;

  const u16* Abase = A + (size_t)(bm * 64) * K;
  const u16* Bbase = Bt + (size_t)(bn * 128) * K;

  // stage: unit u = row*8 + phys_slot; source col = (phys^row&7) slot.
  auto stage = [&](int buf, int k0) {
#pragma unroll
    for (int r = 0; r < 2; r++) {               // A: 512 units
      int u = tid + r * 256;
      int row = u >> 3, slot = u & 7;
      glds16(Abase + (size_t)row * K + k0 + ((slot ^ (row & 7)) << 3),
             &As[buf][u * 8]);
    }
#pragma unroll
    for (int r = 0; r < 4; r++) {               // B: 1024 units
      int u = tid + r * 256;
      int row = u >> 3, slot = u & 7;
      glds16(Bbase + (size_t)row * K + k0 + ((slot ^ (row & 7)) << 3),
             &Bs[buf][u * 8]);
    }
  };

  int sx = lrow & 7;
  int x0 = (g ^ sx) * 8;            // ks=0: logical slot g
  int x1 = ((4 + g) ^ sx) * 8;      // ks=1: logical slot 4+g

  f32x4 acc[2][4];
#pragma unroll
  for (int m = 0; m < 2; m++)
#pragma unroll
    for (int n = 0; n < 4; n++) acc[m][n] = {0.f, 0.f, 0.f, 0.f};

  int nk = K >> 6;
  stage(0, 0);
  for (int kt = 0; kt < nk; ++kt) {
    int buf = kt & 1;
    __syncthreads();
    if (kt + 1 < nk) stage(buf ^ 1, (kt + 1) << 6);
#pragma unroll
    for (int ks = 0; ks < 2; ks++) {
      int xs = ks ? x1 : x0;
      bf16x8 af[2], bfr[4];
#pragma unroll
      for (int m = 0; m < 2; m++)
        af[m] = *(const bf16x8*)&As[buf][(wr + m * 16 + lrow) * 64 + xs];
#pragma unroll
      for (int n = 0; n < 4; n++)
        bfr[n] = *(const bf16x8*)&Bs[buf][(wc + n * 16 + lrow) * 64 + xs];
      __builtin_amdgcn_s_setprio(1);
#pragma unroll
      for (int m = 0; m < 2; m++)
#pragma unroll
        for (int n = 0; n < 4; n++)
          acc[m][n] = __builtin_amdgcn_mfma_f32_16x16x32_bf16(
              af[m], bfr[n], acc[m][n], 0, 0, 0);
      __builtin_amdgcn_s_setprio(0);
    }
  }

#pragma unroll
  for (int m = 0; m < 2; m++) {
    int row0 = bm * 64 + wr + m * 16 + g * 4;
#pragma unroll
    for (int n = 0; n < 4; n++) {
      int col = bn * 128 + wc + n * 16 + lrow;
      gemm_epi<EPI>(acc[m][n], row0, col, bias[col], resid, outp, Nmat);
    }
  }
}

// ---------------------------------------------------------------- attention
// ROUND-11 VERSION (measured best: 60.8us, VALUBusy 47%). flash-style,
// SWAPPED QK^T, glds-staged swizzled K / V^T tiles, defer-max (T13, THR=8),
// 8 waves x 16 q-rows, bijective XCD swizzle. __expf + f2bfu retained:
// round-12's exp2f/pk2 "optimization" RAISED VALUBusy to 58% (exp2f carries
// denormal fixup; compiler already fuses bf16 cvt pairs -- m240 lesson).
__global__ __launch_bounds__(512, 4) void k_attn(
    const u16* __restrict__ Q, const u16* __restrict__ Kk,
    const u16* __restrict__ Vt, u16* __restrict__ Z) {
  __shared__ u16 Ks[2][64 * 64];
  __shared__ u16 Vs[2][64 * 64];     // V^T tile: [d][kv]
  __shared__ u32 Psu[8][64 * 9];     // per-wave P repack: [lane][2n+hi]
  int tid = threadIdx.x, lane = tid & 63, wid = tid >> 6;
  int lrow = lane & 15, g = lane >> 4;
  int id  = blockIdx.x;
  int nid = (id & 7) * 96 + (id >> 3);
  int bh = nid >> 3;
  int qtile = (nid & 7) * 128;
  size_t base = (size_t)bh * SEQ * DHD;
  int bb = bh / NHD, hh = bh % NHD;
  int qrow0 = qtile + wid * 16;

  bf16x8 qf[2];
#pragma unroll
  for (int ks = 0; ks < 2; ks++)
    qf[ks] = *(const bf16x8*)(Q + base + (size_t)(qrow0 + lrow) * DHD +
                              ks * 32 + g * 8);

  f32x4 accO[4];
  float mrun = -1e30f, lrun = 0.f;
#pragma unroll
  for (int n = 0; n < 4; n++) accO[n] = {0.f, 0.f, 0.f, 0.f};

  int srow = tid >> 3;
  int swz  = (((tid & 7) * 16) ^ ((srow & 7) << 4)) >> 1;   // u16 units
  const u16* kg0 = Kk + base + (size_t)srow * DHD + swz;
  const u16* vg0 = Vt + base + (size_t)srow * SEQ + swz;

  auto stageKV = [&](int buf, int t) {
    glds16(kg0 + (size_t)t * 64 * DHD, &Ks[buf][tid * 8]);
    glds16(vg0 + t * 64,               &Vs[buf][tid * 8]);
  };

  int rc0 = ((g * 16)      ^ ((lrow & 7) << 4)) >> 1;
  int rc1 = ((64 + g * 16) ^ ((lrow & 7) << 4)) >> 1;

  stageKV(0, 0);
  for (int t = 0; t < 16; ++t) {
    int buf = t & 1;
    __syncthreads();
    if (t + 1 < 16) stageKV(buf ^ 1, t + 1);

    f32x4 sacc[4];
    __builtin_amdgcn_s_setprio(1);
#pragma unroll
    for (int n = 0; n < 4; n++) {
      bf16x8 kf0 = *(const bf16x8*)&Ks[buf][(n * 16 + lrow) * 64 + rc0];
      bf16x8 kf1 = *(const bf16x8*)&Ks[buf][(n * 16 + lrow) * 64 + rc1];
      sacc[n] = {0.f, 0.f, 0.f, 0.f};
      sacc[n] = __builtin_amdgcn_mfma_f32_16x16x32_bf16(kf0, qf[0], sacc[n], 0, 0, 0);
      sacc[n] = __builtin_amdgcn_mfma_f32_16x16x32_bf16(kf1, qf[1], sacc[n], 0, 0, 0);
    }
    __builtin_amdgcn_s_setprio(0);

    float mx = fmaxf(fmaxf(fmaxf(sacc[0][0], sacc[0][1]),
                           fmaxf(sacc[0][2], sacc[0][3])),
                     fmaxf(fmaxf(sacc[1][0], sacc[1][1]),
                           fmaxf(sacc[1][2], sacc[1][3])));
    mx = fmaxf(mx, fmaxf(fmaxf(fmaxf(sacc[2][0], sacc[2][1]),
                               fmaxf(sacc[2][2], sacc[2][3])),
                         fmaxf(fmaxf(sacc[3][0], sacc[3][1]),
                               fmaxf(sacc[3][2], sacc[3][3]))));
    mx *= 0.125f;
    mx = fmaxf(mx, __shfl_xor(mx, 16, 64));
    mx = fmaxf(mx, __shfl_xor(mx, 32, 64));

    if (__all(mx <= mrun + 8.f)) {
      float psum = 0.f;
#pragma unroll
      for (int n = 0; n < 4; n++)
#pragma unroll
        for (int r = 0; r < 4; r++) {
          float p = __expf(sacc[n][r] * 0.125f - mrun);
          sacc[n][r] = p;
          psum += p;
        }
      psum += __shfl_xor(psum, 16, 64);
      psum += __shfl_xor(psum, 32, 64);
      lrun += psum;
    } else {
      float mnew = fmaxf(mrun, mx);
      float alpha = __expf(mrun - mnew);
      float psum = 0.f;
#pragma unroll
      for (int n = 0; n < 4; n++)
#pragma unroll
        for (int r = 0; r < 4; r++) {
          float p = __expf(sacc[n][r] * 0.125f - mnew);
          sacc[n][r] = p;
          psum += p;
        }
      psum += __shfl_xor(psum, 16, 64);
      psum += __shfl_xor(psum, 32, 64);
      lrun = lrun * alpha + psum;
      mrun = mnew;
#pragma unroll
      for (int r = 0; r < 4; r++) {
        float ar = __shfl(alpha, (lane & 48) | (g * 4 + r), 64);
#pragma unroll
        for (int n = 0; n < 4; n++) accO[n][r] *= ar;
      }
    }

#pragma unroll
    for (int n = 0; n < 4; n++) {
      u32 lo = (u32)f2bfu(sacc[n][0]) | ((u32)f2bfu(sacc[n][1]) << 16);
      u32 hi = (u32)f2bfu(sacc[n][2]) | ((u32)f2bfu(sacc[n][3]) << 16);
      Psu[wid][lane * 9 + 2 * n]     = lo;
      Psu[wid][lane * 9 + 2 * n + 1] = hi;
    }

    int laneA = lrow + ((g & 1) << 5);
    int laneB = laneA + 16;
    int nsel = g >> 1;
    __builtin_amdgcn_s_setprio(1);
#pragma unroll
    for (int ks = 0; ks < 2; ks++) {
      int nks = 2 * ks + nsel;
      union { bf16x8 v; u32 w[4]; } pk;
      pk.w[0] = Psu[wid][laneA * 9 + 2 * nks];
      pk.w[1] = Psu[wid][laneA * 9 + 2 * nks + 1];
      pk.w[2] = Psu[wid][laneB * 9 + 2 * nks];
      pk.w[3] = Psu[wid][laneB * 9 + 2 * nks + 1];
      int rc = ks ? rc1 : rc0;
#pragma unroll
      for (int n = 0; n < 4; n++) {
        bf16x8 vf = *(const bf16x8*)&Vs[buf][(n * 16 + lrow) * 64 + rc];
        accO[n] = __builtin_amdgcn_mfma_f32_16x16x32_bf16(pk.v, vf,
                                                          accO[n], 0, 0, 0);
      }
    }
    __builtin_amdgcn_s_setprio(0);
  }

#pragma unroll
  for (int r = 0; r < 4; r++) {
    float lr = __shfl(lrun, (lane & 48) | (g * 4 + r), 64);
    float inv = 1.f / lr;
    int qrow = qrow0 + g * 4 + r;
#pragma unroll
    for (int n = 0; n < 4; n++) {
      int d = n * 16 + lrow;
      Z[((size_t)(bb * SEQ + qrow)) * CH + hh * DHD + d] =
          f2bfu(accO[n][r] * inv);
    }
  }
}

// ---------------------------------------------------------------- launch
extern "C" void kernel_launch(void* const* d_in, const int* in_sizes, int n_in,
                              void* d_out, int out_size, void* d_ws,
                              size_t ws_size, hipStream_t stream) {
  (void)in_sizes; (void)n_in; (void)out_size; (void)ws_size;
  const float* x   = (const float*)d_in[0];
  const float* Wq  = (const float*)d_in[1];
  const float* bq  = (const float*)d_in[2];
  const float* Wk  = (const float*)d_in[3];
  const float* bk  = (const float*)d_in[4];
  const float* Wv  = (const float*)d_in[5];
  const float* bv  = (const float*)d_in[6];
  const float* Wo  = (const float*)d_in[7];
  const float* bo  = (const float*)d_in[8];
  const float* g1  = (const float*)d_in[9];
  const float* b1  = (const float*)d_in[10];
  const float* g2  = (const float*)d_in[11];
  const float* b2  = (const float*)d_in[12];
  const float* W1  = (const float*)d_in[13];
  const float* bf1 = (const float*)d_in[14];
  const float* W2  = (const float*)d_in[15];
  const float* bf2 = (const float*)d_in[16];

  u16* wsu  = (u16*)d_ws;
  u16* wq_t = wsu;                               // [3C][C] packed q,k,v
  u16* wo_t = wq_t + (size_t)3 * CH * CH;
  u16* w1_t = wo_t + (size_t)CH * CH;            // [FF][C]
  u16* w2_t = w1_t + (size_t)CH * FFD;           // [C][FF]
  u16* xn   = w2_t + (size_t)CH * FFD;           // [M][C]
  u16* qb   = xn + (size_t)MR * CH;              // q,k: [B*H][N][DH]; v: [B*H][DH][N]
  u16* zb   = qb + (size_t)3 * MR * CH;          // [B][N][C]
  float* bres = (float*)(zb + (size_t)MR * CH);  // [M][C] fp32
  u16* hb   = qb;                                // reuse region: [M][FF]
  float* bqkv = (float*)d_out;                   // packed bias (overwritten)

  dim3 blk(256);
  k_transpose_all<<<6921, blk, 0, stream>>>(Wq, Wk, Wv, Wo, W1, W2, wsu,
                                            bq, bk, bv, bqkv);

  k_layernorm_bf16<<<2048, blk, 0, stream>>>(x, g1, b1, xn);
  k_gemmk64<EPI_QKV><<<dim3(128, 18), blk, 0, stream>>>(
      xn, wq_t, bqkv, nullptr, qb, CH, 3 * CH);
  k_attn<<<768, dim3(512), 0, stream>>>(qb, qb + (size_t)MR * CH,
                                        qb + (size_t)2 * MR * CH, zb);
  k_gemmk64<EPI_RESID><<<dim3(128, 6), blk, 0, stream>>>(
      zb, wo_t, bo, x, bres, CH, CH);
  k_layernorm_bf16<<<2048, blk, 0, stream>>>(bres, g2, b2, xn);
  k_gemmk64<EPI_RELU><<<dim3(128, 24), blk, 0, stream>>>(
      xn, w1_t, bf1, nullptr, hb, CH, FFD);
  k_gemmk64<EPI_RESID><<<dim3(128, 6), blk, 0, stream>>>(
      hb, w2_t, bf2, bres, (float*)d_out, FFD, CH);
}

// Round 14
// 234.195 us; speedup vs baseline: 1.3586x; 1.0127x over previous
//
#include <hip/hip_runtime.h>
#include <hip/hip_bf16.h>

// ViT encoder block: B=8, N=1024, C=768, H=12, DH=64, FF=3072, fp32 in/out,
// bf16 MFMA compute internally.
#define BDIM 8
#define SEQ  1024
#define CH   768
#define NHD  12
#define DHD  64
#define FFD  3072
#define MR   (BDIM*SEQ)   // 8192 token rows

typedef __attribute__((ext_vector_type(8))) short bf16x8;
typedef __attribute__((ext_vector_type(4))) float f32x4;
typedef unsigned int   u32;
typedef unsigned short u16;

#define QSCL 0.18033688f   // 0.125 * log2(e): Q pre-scale -> scores in log2

__device__ __forceinline__ u16 f2bfu(float x) {
  __hip_bfloat16 h = __float2bfloat16(x);
  return *reinterpret_cast<u16*>(&h);
}

__device__ __forceinline__ void glds16(const void* g, void* l) {
  __builtin_amdgcn_global_load_lds(
      (const __attribute__((address_space(1))) u32*)g,
      (__attribute__((address_space(3))) u32*)l, 16, 0, 0);
}

// ---------------------------------------------------------------- transpose
// All 6 weights + bias pack in one launch. W [K][Nc] fp32 -> Wt [Nc][K] bf16.
// Blocks >= 6912 pack bq|bk|bv into bdst (float[2304]).
__global__ __launch_bounds__(256) void k_transpose_all(
    const float* __restrict__ Wq, const float* __restrict__ Wk,
    const float* __restrict__ Wv, const float* __restrict__ Wo,
    const float* __restrict__ W1, const float* __restrict__ W2,
    u16* __restrict__ ws, const float* __restrict__ bq,
    const float* __restrict__ bk, const float* __restrict__ bv,
    float* __restrict__ bdst) {
  __shared__ float tile[32][33];
  int b = blockIdx.x;
  if (b >= 6912) {
    int i = (b - 6912) * 256 + threadIdx.x;
    if (i < 3 * CH)
      bdst[i] = i < CH ? bq[i] : (i < 2 * CH ? bk[i - CH] : bv[i - 2 * CH]);
    return;
  }
  int id, tb;
  if (b < 2304)      { id = b / 576; tb = b % 576; }
  else if (b < 4608) { id = 4;       tb = b - 2304; }
  else               { id = 5;       tb = b - 4608; }
  const float* src;
  u16* dst;
  int K, Nc;
  switch (id) {
    case 0: src = Wq; dst = ws;                      K = CH;  Nc = CH;  break;
    case 1: src = Wk; dst = ws + (size_t)CH*CH;      K = CH;  Nc = CH;  break;
    case 2: src = Wv; dst = ws + (size_t)2*CH*CH;    K = CH;  Nc = CH;  break;
    case 3: src = Wo; dst = ws + (size_t)3*CH*CH;    K = CH;  Nc = CH;  break;
    case 4: src = W1; dst = ws + (size_t)4*CH*CH;    K = CH;  Nc = FFD; break;
    default:src = W2; dst = ws + (size_t)4*CH*CH + (size_t)CH*FFD;
                                                     K = FFD; Nc = CH;  break;
  }
  int tilesx = Nc >> 5;
  int bx = (tb % tilesx) * 32;        // Nc dim
  int by = (tb / tilesx) * 32;        // K dim
  int tx = threadIdx.x & 31, ty = threadIdx.x >> 5;   // 32 x 8
#pragma unroll
  for (int j = 0; j < 32; j += 8)
    tile[ty + j][tx] = src[(size_t)(by + ty + j) * Nc + bx + tx];
  __syncthreads();
#pragma unroll
  for (int j = 0; j < 32; j += 8)
    dst[(size_t)(bx + ty + j) * K + by + tx] = f2bfu(tile[tx][ty + j]);
}

// ---------------------------------------------------------------- layernorm
__global__ __launch_bounds__(256) void k_layernorm_bf16(
    const float* __restrict__ src, const float* __restrict__ gamma,
    const float* __restrict__ beta, u16* __restrict__ dst) {
  int row  = blockIdx.x * 4 + (threadIdx.x >> 6);
  int lane = threadIdx.x & 63;
  const float4* p4 = (const float4*)(src + (size_t)row * CH);
  float4 v[3];
  float s = 0.f, s2 = 0.f;
#pragma unroll
  for (int k = 0; k < 3; k++) {
    v[k] = p4[lane + k * 64];
    s  += v[k].x + v[k].y + v[k].z + v[k].w;
    s2 += v[k].x * v[k].x + v[k].y * v[k].y + v[k].z * v[k].z + v[k].w * v[k].w;
  }
#pragma unroll
  for (int m = 1; m < 64; m <<= 1) {
    s  += __shfl_xor(s,  m, 64);
    s2 += __shfl_xor(s2, m, 64);
  }
  float mean = s * (1.f / CH);
  float var  = s2 * (1.f / CH) - mean * mean;
  float rs   = rsqrtf(var + 1e-5f);
  u16* drow = dst + (size_t)row * CH;
#pragma unroll
  for (int k = 0; k < 3; k++) {
    int col = lane * 4 + k * 256;
    float4 gq = ((const float4*)gamma)[lane + k * 64];
    float4 bq = ((const float4*)beta )[lane + k * 64];
    u32 lo = (u32)f2bfu((v[k].x - mean) * rs * gq.x + bq.x) |
             ((u32)f2bfu((v[k].y - mean) * rs * gq.y + bq.y) << 16);
    u32 hi = (u32)f2bfu((v[k].z - mean) * rs * gq.z + bq.z) |
             ((u32)f2bfu((v[k].w - mean) * rs * gq.w + bq.w) << 16);
    uint2 w; w.x = lo; w.y = hi;
    *(uint2*)(drow + col) = w;
  }
}

enum { EPI_QKV = 0, EPI_RESID = 1, EPI_RELU = 2 };

// ------------------------------------------------- shared epilogue (16x16)
// D row = (lane>>4)*4 + r, col = lane&15 (m89-verified mapping). row0 % 4 == 0.
// EPI_QKV: Q (sel==0) is PRE-SCALED by QSCL so attn scores arrive in log2
// domain (saves the per-element scale+log2e mul in the softmax inner loop).
template <int EPI>
__device__ __forceinline__ void gemm_epi(const f32x4& a, int row0, int col,
                                         float bval, const float* resid,
                                         void* outp, int Nmat) {
  if constexpr (EPI == EPI_QKV) {
    int sel = col / CH;                       // 128-col tile is within one sel
    int c = col - sel * CH;
    int h = c >> 6, d = c & 63;
    int bb = row0 >> 10, nn0 = row0 & (SEQ - 1);
    if (sel == 2) {
      // V stored TRANSPOSED per head: [B*H][DH][N]; 4 consecutive token rows
      union { uint2 u; u16 h4[4]; } pk;
#pragma unroll
      for (int r = 0; r < 4; r++) pk.h4[r] = f2bfu(a[r] + bval);
      *(uint2*)&((u16*)outp)[(size_t)2 * MR * CH +
                             (((size_t)(bb * NHD + h)) * DHD + d) * SEQ + nn0] =
          pk.u;
    } else {
      float scl = (sel == 0) ? QSCL : 1.f;    // uniform per col-tile
#pragma unroll
      for (int r = 0; r < 4; r++)
        ((u16*)outp)[(size_t)sel * MR * CH +
                     (((size_t)(bb * NHD + h)) * SEQ + nn0 + r) * DHD + d] =
            f2bfu((a[r] + bval) * scl);
    }
  } else if constexpr (EPI == EPI_RESID) {
#pragma unroll
    for (int r = 0; r < 4; r++) {
      size_t idx = (size_t)(row0 + r) * Nmat + col;
      ((float*)outp)[idx] = a[r] + bval + resid[idx];
    }
  } else {  // RELU -> bf16 row-major
#pragma unroll
    for (int r = 0; r < 4; r++) {
      float val = a[r] + bval;
      ((u16*)outp)[(size_t)(row0 + r) * Nmat + col] =
          f2bfu(val > 0.f ? val : 0.f);
    }
  }
}

// ---------------------------------------------------------------- GEMM BK64
// Round-11/12 proven: TM=64, BN=128, BK=64 -> half the barrier+drain count
// of BK=32 at identical per-64-K-col MFMA/ds/glds counts; conflicts held at
// 0 by the row&7 XOR swizzle on pre-swizzled global source (dest linear,
// rule #21) + reads. LDS 48KB -> 3 blk/CU. Natural dispatch. All four GEMMs.
template <int EPI>
__global__ __launch_bounds__(256, 2) void k_gemmk64(
    const u16* __restrict__ A, const u16* __restrict__ Bt,
    const float* __restrict__ bias, const float* __restrict__ resid,
    void* __restrict__ outp, int K, int Nmat) {
  __shared__ u16 As[2][64 * 64];
  __shared__ u16 Bs[2][128 * 64];
  int tid = threadIdx.x;
  int bm = blockIdx.x, bn = blockIdx.y;
  int lane = tid & 63, wid = tid >> 6;
  int wr = (wid >> 1) * 32, wc = (wid & 1) * 64;
  int lrow = lane & 15, g = lane >> 4;

  const u16* Abase = A + (size_t)(bm * 64) * K;
  const u16* Bbase = Bt + (size_t)(bn * 128) * K;

  // stage: unit u = row*8 + phys_slot; source col = (phys^row&7) slot.
  auto stage = [&](int buf, int k0) {
#pragma unroll
    for (int r = 0; r < 2; r++) {               // A: 512 units
      int u = tid + r * 256;
      int row = u >> 3, slot = u & 7;
      glds16(Abase + (size_t)row * K + k0 + ((slot ^ (row & 7)) << 3),
             &As[buf][u * 8]);
    }
#pragma unroll
    for (int r = 0; r < 4; r++) {               // B: 1024 units
      int u = tid + r * 256;
      int row = u >> 3, slot = u & 7;
      glds16(Bbase + (size_t)row * K + k0 + ((slot ^ (row & 7)) << 3),
             &Bs[buf][u * 8]);
    }
  };

  int sx = lrow & 7;
  int x0 = (g ^ sx) * 8;            // ks=0: logical slot g
  int x1 = ((4 + g) ^ sx) * 8;      // ks=1: logical slot 4+g

  f32x4 acc[2][4];
#pragma unroll
  for (int m = 0; m < 2; m++)
#pragma unroll
    for (int n = 0; n < 4; n++) acc[m][n] = {0.f, 0.f, 0.f, 0.f};

  int nk = K >> 6;
  stage(0, 0);
  for (int kt = 0; kt < nk; ++kt) {
    int buf = kt & 1;
    __syncthreads();
    if (kt + 1 < nk) stage(buf ^ 1, (kt + 1) << 6);
#pragma unroll
    for (int ks = 0; ks < 2; ks++) {
      int xs = ks ? x1 : x0;
      bf16x8 af[2], bfr[4];
#pragma unroll
      for (int m = 0; m < 2; m++)
        af[m] = *(const bf16x8*)&As[buf][(wr + m * 16 + lrow) * 64 + xs];
#pragma unroll
      for (int n = 0; n < 4; n++)
        bfr[n] = *(const bf16x8*)&Bs[buf][(wc + n * 16 + lrow) * 64 + xs];
      __builtin_amdgcn_s_setprio(1);
#pragma unroll
      for (int m = 0; m < 2; m++)
#pragma unroll
        for (int n = 0; n < 4; n++)
          acc[m][n] = __builtin_amdgcn_mfma_f32_16x16x32_bf16(
              af[m], bfr[n], acc[m][n], 0, 0, 0);
      __builtin_amdgcn_s_setprio(0);
    }
  }

#pragma unroll
  for (int m = 0; m < 2; m++) {
    int row0 = bm * 64 + wr + m * 16 + g * 4;
#pragma unroll
    for (int n = 0; n < 4; n++) {
      int col = bn * 128 + wc + n * 16 + lrow;
      gemm_epi<EPI>(acc[m][n], row0, col, bias[col], resid, outp, Nmat);
    }
  }
}

// ---------------------------------------------------------------- attention
// flash-style, SWAPPED QK^T, glds-staged swizzled K / V^T tiles, defer-max
// (T13), 8 waves x 16 q-rows, bijective XCD swizzle. Round-14 VALU cuts:
// (1) Q pre-scaled by QSCL -> scores in log2 domain; p = raw v_exp_f32
//     (__builtin_amdgcn_exp2f) of (s - m): 2 ops/elem (round-12's libm
//     exp2f regression was its denormal fixup, not the HW op).
// (2) row-sum (softmax denominator) via MFMA with ones-B: accS matches
//     accO's layout & rescale path; kills psum tree + lrun + final shfls.
// (3) max3 tree (8 ops vs 15).
__global__ __launch_bounds__(512, 4) void k_attn(
    const u16* __restrict__ Q, const u16* __restrict__ Kk,
    const u16* __restrict__ Vt, u16* __restrict__ Z) {
  __shared__ u16 Ks[2][64 * 64];
  __shared__ u16 Vs[2][64 * 64];     // V^T tile: [d][kv]
  __shared__ u32 Psu[8][64 * 9];     // per-wave P repack: [lane][2n+hi]
  int tid = threadIdx.x, lane = tid & 63, wid = tid >> 6;
  int lrow = lane & 15, g = lane >> 4;
  int id  = blockIdx.x;
  int nid = (id & 7) * 96 + (id >> 3);
  int bh = nid >> 3;
  int qtile = (nid & 7) * 128;
  size_t base = (size_t)bh * SEQ * DHD;
  int bb = bh / NHD, hh = bh % NHD;
  int qrow0 = qtile + wid * 16;

  bf16x8 qf[2];
#pragma unroll
  for (int ks = 0; ks < 2; ks++)
    qf[ks] = *(const bf16x8*)(Q + base + (size_t)(qrow0 + lrow) * DHD +
                              ks * 32 + g * 8);

  bf16x8 vone;
#pragma unroll
  for (int j = 0; j < 8; j++) vone[j] = (short)0x3F80;   // bf16 1.0

  f32x4 accO[4];
  f32x4 accS = {0.f, 0.f, 0.f, 0.f};   // denominator, same layout as accO
  float mrun = -1e30f;                  // log2 units
#pragma unroll
  for (int n = 0; n < 4; n++) accO[n] = {0.f, 0.f, 0.f, 0.f};

  int srow = tid >> 3;
  int swz  = (((tid & 7) * 16) ^ ((srow & 7) << 4)) >> 1;   // u16 units
  const u16* kg0 = Kk + base + (size_t)srow * DHD + swz;
  const u16* vg0 = Vt + base + (size_t)srow * SEQ + swz;

  auto stageKV = [&](int buf, int t) {
    glds16(kg0 + (size_t)t * 64 * DHD, &Ks[buf][tid * 8]);
    glds16(vg0 + t * 64,               &Vs[buf][tid * 8]);
  };

  int rc0 = ((g * 16)      ^ ((lrow & 7) << 4)) >> 1;
  int rc1 = ((64 + g * 16) ^ ((lrow & 7) << 4)) >> 1;

  auto mx3 = [](float a, float b, float c) { return fmaxf(fmaxf(a, b), c); };

  stageKV(0, 0);
  for (int t = 0; t < 16; ++t) {
    int buf = t & 1;
    __syncthreads();
    if (t + 1 < 16) stageKV(buf ^ 1, t + 1);

    f32x4 sacc[4];
    __builtin_amdgcn_s_setprio(1);
#pragma unroll
    for (int n = 0; n < 4; n++) {
      bf16x8 kf0 = *(const bf16x8*)&Ks[buf][(n * 16 + lrow) * 64 + rc0];
      bf16x8 kf1 = *(const bf16x8*)&Ks[buf][(n * 16 + lrow) * 64 + rc1];
      sacc[n] = {0.f, 0.f, 0.f, 0.f};
      sacc[n] = __builtin_amdgcn_mfma_f32_16x16x32_bf16(kf0, qf[0], sacc[n], 0, 0, 0);
      sacc[n] = __builtin_amdgcn_mfma_f32_16x16x32_bf16(kf1, qf[1], sacc[n], 0, 0, 0);
    }
    __builtin_amdgcn_s_setprio(0);

    // max over 16 in-lane values (log2 domain) via max3 tree, then 2 shfls
    float a0 = mx3(sacc[0][0], sacc[0][1], sacc[0][2]);
    float a1 = mx3(sacc[0][3], sacc[1][0], sacc[1][1]);
    float a2 = mx3(sacc[1][2], sacc[1][3], sacc[2][0]);
    float a3 = mx3(sacc[2][1], sacc[2][2], sacc[2][3]);
    float a4 = mx3(sacc[3][0], sacc[3][1], sacc[3][2]);
    float mx = fmaxf(mx3(a0, a1, a2), mx3(a3, a4, sacc[3][3]));
    mx = fmaxf(mx, __shfl_xor(mx, 16, 64));
    mx = fmaxf(mx, __shfl_xor(mx, 32, 64));

    if (__all(mx <= mrun + 11.54f)) {   // 8 nats in bits
#pragma unroll
      for (int n = 0; n < 4; n++)
#pragma unroll
        for (int r = 0; r < 4; r++)
          sacc[n][r] = __builtin_amdgcn_exp2f(sacc[n][r] - mrun);
    } else {
      float mnew = fmaxf(mrun, mx);
      float alpha = __builtin_amdgcn_exp2f(mrun - mnew);
#pragma unroll
      for (int n = 0; n < 4; n++)
#pragma unroll
        for (int r = 0; r < 4; r++)
          sacc[n][r] = __builtin_amdgcn_exp2f(sacc[n][r] - mnew);
      mrun = mnew;
#pragma unroll
      for (int r = 0; r < 4; r++) {
        float ar = __shfl(alpha, (lane & 48) | (g * 4 + r), 64);
        accS[r] *= ar;
#pragma unroll
        for (int n = 0; n < 4; n++) accO[n][r] *= ar;
      }
    }

#pragma unroll
    for (int n = 0; n < 4; n++) {
      u32 lo = (u32)f2bfu(sacc[n][0]) | ((u32)f2bfu(sacc[n][1]) << 16);
      u32 hi = (u32)f2bfu(sacc[n][2]) | ((u32)f2bfu(sacc[n][3]) << 16);
      Psu[wid][lane * 9 + 2 * n]     = lo;
      Psu[wid][lane * 9 + 2 * n + 1] = hi;
    }

    int laneA = lrow + ((g & 1) << 5);
    int laneB = laneA + 16;
    int nsel = g >> 1;
    __builtin_amdgcn_s_setprio(1);
#pragma unroll
    for (int ks = 0; ks < 2; ks++) {
      int nks = 2 * ks + nsel;
      union { bf16x8 v; u32 w[4]; } pk;
      pk.w[0] = Psu[wid][laneA * 9 + 2 * nks];
      pk.w[1] = Psu[wid][laneA * 9 + 2 * nks + 1];
      pk.w[2] = Psu[wid][laneB * 9 + 2 * nks];
      pk.w[3] = Psu[wid][laneB * 9 + 2 * nks + 1];
      int rc = ks ? rc1 : rc0;
#pragma unroll
      for (int n = 0; n < 4; n++) {
        bf16x8 vf = *(const bf16x8*)&Vs[buf][(n * 16 + lrow) * 64 + rc];
        accO[n] = __builtin_amdgcn_mfma_f32_16x16x32_bf16(pk.v, vf,
                                                          accO[n], 0, 0, 0);
      }
      // denominator: row-sum of the SAME bf16 P fed to PV
      accS = __builtin_amdgcn_mfma_f32_16x16x32_bf16(pk.v, vone, accS, 0, 0, 0);
    }
    __builtin_amdgcn_s_setprio(0);
  }

  // normalize + write z token-major [B][N][C] bf16; accS[r] is already in
  // this lane's (q=g*4+r, d=lrow) position -- no shfl needed.
#pragma unroll
  for (int r = 0; r < 4; r++) {
    float inv = 1.f / accS[r];
    int qrow = qrow0 + g * 4 + r;
#pragma unroll
    for (int n = 0; n < 4; n++) {
      int d = n * 16 + lrow;
      Z[((size_t)(bb * SEQ + qrow)) * CH + hh * DHD + d] =
          f2bfu(accO[n][r] * inv);
    }
  }
}

// ---------------------------------------------------------------- launch
extern "C" void kernel_launch(void* const* d_in, const int* in_sizes, int n_in,
                              void* d_out, int out_size, void* d_ws,
                              size_t ws_size, hipStream_t stream) {
  (void)in_sizes; (void)n_in; (void)out_size; (void)ws_size;
  const float* x   = (const float*)d_in[0];
  const float* Wq  = (const float*)d_in[1];
  const float* bq  = (const float*)d_in[2];
  const float* Wk  = (const float*)d_in[3];
  const float* bk  = (const float*)d_in[4];
  const float* Wv  = (const float*)d_in[5];
  const float* bv  = (const float*)d_in[6];
  const float* Wo  = (const float*)d_in[7];
  const float* bo  = (const float*)d_in[8];
  const float* g1  = (const float*)d_in[9];
  const float* b1  = (const float*)d_in[10];
  const float* g2  = (const float*)d_in[11];
  const float* b2  = (const float*)d_in[12];
  const float* W1  = (const float*)d_in[13];
  const float* bf1 = (const float*)d_in[14];
  const float* W2  = (const float*)d_in[15];
  const float* bf2 = (const float*)d_in[16];

  u16* wsu  = (u16*)d_ws;
  u16* wq_t = wsu;                               // [3C][C] packed q,k,v
  u16* wo_t = wq_t + (size_t)3 * CH * CH;
  u16* w1_t = wo_t + (size_t)CH * CH;            // [FF][C]
  u16* w2_t = w1_t + (size_t)CH * FFD;           // [C][FF]
  u16* xn   = w2_t + (size_t)CH * FFD;           // [M][C]
  u16* qb   = xn + (size_t)MR * CH;              // q,k: [B*H][N][DH]; v: [B*H][DH][N]
  u16* zb   = qb + (size_t)3 * MR * CH;          // [B][N][C]
  float* bres = (float*)(zb + (size_t)MR * CH);  // [M][C] fp32
  u16* hb   = qb;                                // reuse region: [M][FF]
  float* bqkv = (float*)d_out;                   // packed bias (overwritten)

  dim3 blk(256);
  k_transpose_all<<<6921, blk, 0, stream>>>(Wq, Wk, Wv, Wo, W1, W2, wsu,
                                            bq, bk, bv, bqkv);

  k_layernorm_bf16<<<2048, blk, 0, stream>>>(x, g1, b1, xn);
  k_gemmk64<EPI_QKV><<<dim3(128, 18), blk, 0, stream>>>(
      xn, wq_t, bqkv, nullptr, qb, CH, 3 * CH);
  k_attn<<<768, dim3(512), 0, stream>>>(qb, qb + (size_t)MR * CH,
                                        qb + (size_t)2 * MR * CH, zb);
  k_gemmk64<EPI_RESID><<<dim3(128, 6), blk, 0, stream>>>(
      zb, wo_t, bo, x, bres, CH, CH);
  k_layernorm_bf16<<<2048, blk, 0, stream>>>(bres, g2, b2, xn);
  k_gemmk64<EPI_RELU><<<dim3(128, 24), blk, 0, stream>>>(
      xn, w1_t, bf1, nullptr, hb, CH, FFD);
  k_gemmk64<EPI_RESID><<<dim3(128, 6), blk, 0, stream>>>(
      hb, w2_t, bf2, bres, (float*)d_out, FFD, CH);
}